// Round 5
// baseline (423.420 us; speedup 1.0000x reference)
//
#include <hip/hip_runtime.h>
#include <math.h>

// ---------------------------------------------------------------------------
// RGAPConv, CSR-gather formulation (R5):
//   node:      tiled GEMM with bf16 LDS tiles (68 KB -> 2 blocks/CU, 1 round);
//              fp32 scalar packs from global x; Vm emitted packed bf16.
//   edge1:     e_val/gamma/b + dst histogram.
//   CSR build: fused single-block scan -> scatter 8B payload {e_val, src|t<<27}.
//   gather:    one wave per dst node, shuffle softmax, batch-4 unrolled
//              accumulation (4 Vmb loads in flight). alpha via coalesced kernel.
// ---------------------------------------------------------------------------

__device__ __forceinline__ float wave_max(float v) {
    #pragma unroll
    for (int o = 32; o > 0; o >>= 1) v = fmaxf(v, __shfl_xor(v, o, 64));
    return v;
}
__device__ __forceinline__ float wave_sum(float v) {
    #pragma unroll
    for (int o = 32; o > 0; o >>= 1) v += __shfl_xor(v, o, 64);
    return v;
}

__device__ __forceinline__ unsigned bf16rne(float f) {
    unsigned u = __float_as_uint(f);
    return (u + 0x7FFFu + ((u >> 16) & 1u)) >> 16;  // round-to-nearest-even
}
__device__ __forceinline__ float bflo(unsigned u) { return __uint_as_float(u << 16); }
__device__ __forceinline__ float bfhi(unsigned u) { return __uint_as_float(u & 0xFFFF0000u); }

// grid = 146 blocks x 128 threads. Builds all small tables.
__global__ void __launch_bounds__(128) precompute_kernel(
    const float* __restrict__ Wq, const float* __restrict__ bq,
    const float* __restrict__ Wk, const float* __restrict__ bk,
    const float* __restrict__ Wv, const float* __restrict__ bv,
    const float* __restrict__ rel_emb, const float* __restrict__ attn_vec,
    const float* __restrict__ msg_w, const float* __restrict__ msg_b,
    const float* __restrict__ gnw, const float* __restrict__ grb,
    const float* __restrict__ gnb,
    const float* __restrict__ rule_w1, const float* __restrict__ rule_b1,
    const float* __restrict__ rule_w2,
    unsigned short* __restrict__ W2b, float* __restrict__ c2,
    float* __restrict__ wkA, float* __restrict__ wqA,
    float* __restrict__ wkG, float* __restrict__ wqG,
    float* __restrict__ relA, float* __restrict__ relM,
    float* __restrict__ consts,
    float4* __restrict__ w1t, float2* __restrict__ w12)
{
    __shared__ float red[128];
    int bid = blockIdx.x, j = threadIdx.x;

    auto blk_reduce = [&](float v) -> float {
        red[j] = v;
        __syncthreads();
        for (int s = 64; s > 0; s >>= 1) {
            if (j < s) red[j] += red[j + s];
            __syncthreads();
        }
        float r = red[0];
        __syncthreads();
        return r;
    };

    if (bid < 128) {
        int i = bid;
        float acc = 0.f;
        #pragma unroll 8
        for (int k = 0; k < 128; ++k) acc = fmaf(Wv[i * 128 + k], msg_w[k * 128 + j], acc);
        W2b[i * 128 + j] = (unsigned short)bf16rne(acc);
        float r;
        r = blk_reduce(Wk[i * 128 + j] * attn_vec[j]);        if (j == 0) wkA[i] = r;
        r = blk_reduce(Wq[i * 128 + j] * attn_vec[128 + j]);  if (j == 0) wqA[i] = r;
        r = blk_reduce(Wk[i * 128 + j] * gnw[j]);             if (j == 0) wkG[i] = r;
        r = blk_reduce(Wq[i * 128 + j] * gnw[128 + j]);       if (j == 0) wqG[i] = r;
    } else if (bid < 144) {
        int t = bid - 128;
        float acc = 0.f;
        #pragma unroll 8
        for (int k = 0; k < 128; ++k) acc = fmaf(rel_emb[t * 128 + k], msg_w[k * 128 + j], acc);
        relM[t * 128 + j] = acc;
        float r = blk_reduce(rel_emb[t * 128 + j] * attn_vec[256 + j]);
        if (j == 0) relA[t] = r;
    } else if (bid == 144) {
        float acc = msg_b[j];
        #pragma unroll 8
        for (int k = 0; k < 128; ++k) acc = fmaf(bv[k], msg_w[k * 128 + j], acc);
        c2[j] = acc;
        w1t[j] = make_float4(rule_w1[j], rule_w1[128 + j], rule_w1[256 + j], rule_w1[384 + j]);
        w12[j] = make_float2(rule_b1[j], rule_w2[j]);
    } else {
        float r = blk_reduce(bk[j] * attn_vec[j] + bq[j] * attn_vec[128 + j]);
        if (j == 0) consts[0] = r;
        r = blk_reduce(bk[j] * gnw[j] + bq[j] * gnw[128 + j]);
        if (j == 0) consts[1] = r + grb[0] + gnb[0];
    }
}

// Tiled GEMM, bf16 LDS tiles: 128 rows x 128 cols per block, K=128 resident.
// Asu/Bsu rows padded to 136 shorts (272 B): 16B-aligned b128 reads, <=2-way
// bank aliasing (free). LDS total 68 KB -> 2 blocks/CU, single grid round.
__global__ void __launch_bounds__(256) node_kernel(
    const float4* __restrict__ x4, const unsigned short* __restrict__ W2b,
    const float* __restrict__ c2,
    const float* __restrict__ wkA, const float* __restrict__ wqA,
    const float* __restrict__ wkG, const float* __restrict__ wqG,
    unsigned* __restrict__ Vmb, float2* __restrict__ srcPack,
    float2* __restrict__ dstPack, int* __restrict__ deg, int n_nodes)
{
    __shared__ unsigned short Asu[128][136];
    __shared__ unsigned short Bsu[128][136];
    const int tid = threadIdx.x;
    const int rowBase = blockIdx.x * 128;

    if (tid < 128 && rowBase + tid < n_nodes) deg[rowBase + tid] = 0;

    // stage W2 (bf16): 16384 shorts, 4 per thread-iter, coalesced 8B reads
    #pragma unroll
    for (int l = 0; l < 16; ++l) {
        int flat = l * 256 + tid;        // 4096 quads
        int k = flat >> 5, n4 = flat & 31;
        uint2 w = *(const uint2*)&W2b[k * 128 + n4 * 4];
        *(uint2*)&Bsu[k][n4 * 4] = w;
    }
    // stage x transposed -> bf16 As[k][r]
    #pragma unroll
    for (int l = 0; l < 16; ++l) {
        int flat = l * 256 + tid;
        int r = flat & 127;
        int k4 = flat >> 7;
        int row = rowBase + r;
        float4 v = (row < n_nodes) ? x4[row * 32 + k4] : make_float4(0.f, 0.f, 0.f, 0.f);
        Asu[4 * k4 + 0][r] = (unsigned short)bf16rne(v.x);
        Asu[4 * k4 + 1][r] = (unsigned short)bf16rne(v.y);
        Asu[4 * k4 + 2][r] = (unsigned short)bf16rne(v.z);
        Asu[4 * k4 + 3][r] = (unsigned short)bf16rne(v.w);
    }

    // fp32 per-node scalar packs from global x (L2-hot after staging)
    {
        int r = tid & 127, h = tid >> 7;
        int row = rowBase + r;
        if (row < n_nodes) {
            const float4* wa4 = (const float4*)(h ? wqA : wkA);
            const float4* wg4 = (const float4*)(h ? wqG : wkG);
            float sA = 0.f, sG = 0.f;
            #pragma unroll 8
            for (int k4 = 0; k4 < 32; ++k4) {
                float4 xv = x4[row * 32 + k4];
                float4 wa = wa4[k4], wg = wg4[k4];
                sA = fmaf(xv.x, wa.x, fmaf(xv.y, wa.y, fmaf(xv.z, wa.z, fmaf(xv.w, wa.w, sA))));
                sG = fmaf(xv.x, wg.x, fmaf(xv.y, wg.y, fmaf(xv.z, wg.z, fmaf(xv.w, wg.w, sG))));
            }
            if (h) dstPack[row] = make_float2(sA, sG);
            else   srcPack[row] = make_float2(sA, sG);
        }
    }
    __syncthreads();

    const int tx = tid & 15, ty = tid >> 4;
    float acc[8][8];
    #pragma unroll
    for (int i = 0; i < 8; ++i)
        #pragma unroll
        for (int j = 0; j < 8; ++j) acc[i][j] = 0.f;

    #pragma unroll 2
    for (int k = 0; k < 128; ++k) {
        uint4 au = *(const uint4*)&Asu[k][ty * 8];
        uint4 bu = *(const uint4*)&Bsu[k][tx * 8];
        float a[8] = {bflo(au.x), bfhi(au.x), bflo(au.y), bfhi(au.y),
                      bflo(au.z), bfhi(au.z), bflo(au.w), bfhi(au.w)};
        float b[8] = {bflo(bu.x), bfhi(bu.x), bflo(bu.y), bfhi(bu.y),
                      bflo(bu.z), bfhi(bu.z), bflo(bu.w), bfhi(bu.w)};
        #pragma unroll
        for (int i = 0; i < 8; ++i)
            #pragma unroll
            for (int j = 0; j < 8; ++j)
                acc[i][j] = fmaf(a[i], b[j], acc[i][j]);
    }

    float c2v[8];
    #pragma unroll
    for (int j = 0; j < 8; ++j) c2v[j] = c2[tx * 8 + j];
    #pragma unroll
    for (int i = 0; i < 8; ++i) {
        int row = rowBase + ty * 8 + i;
        if (row < n_nodes) {
            uint4 o;
            o.x = bf16rne(acc[i][0] + c2v[0]) | (bf16rne(acc[i][1] + c2v[1]) << 16);
            o.y = bf16rne(acc[i][2] + c2v[2]) | (bf16rne(acc[i][3] + c2v[3]) << 16);
            o.z = bf16rne(acc[i][4] + c2v[4]) | (bf16rne(acc[i][5] + c2v[5]) << 16);
            o.w = bf16rne(acc[i][6] + c2v[6]) | (bf16rne(acc[i][7] + c2v[7]) << 16);
            *(uint4*)&Vmb[row * 64 + tx * 4] = o;
        }
    }
}

// one thread per edge: e_val, gamma, b + deg histogram
__global__ void __launch_bounds__(256) edge1_kernel(
    const int* __restrict__ ei, const int* __restrict__ et,
    const float4* __restrict__ erf,
    const float4* __restrict__ w1t, const float2* __restrict__ w12,
    const float* __restrict__ rule_b2, const float* __restrict__ grw,
    const float2* __restrict__ srcPack, const float2* __restrict__ dstPack,
    const float* __restrict__ relA, const float* __restrict__ consts,
    float* __restrict__ e_val, float* __restrict__ gamma_out,
    float* __restrict__ b_out, int* __restrict__ deg,
    int n_edges)
{
    __shared__ float4 s_w1t[128];
    __shared__ float2 s_w12[128];
    int tid = threadIdx.x;
    if (tid < 128) { s_w1t[tid] = w1t[tid]; s_w12[tid] = w12[tid]; }
    __syncthreads();
    int e = blockIdx.x * 256 + tid;
    if (e >= n_edges) return;

    int s = ei[e], d = ei[n_edges + e], t = et[e];
    float4 rf = erf[e];
    float2 ss = srcPack[s], dd = dstPack[d];

    float pre = ss.x + dd.x + relA[t] + consts[0];
    float e_base = pre >= 0.f ? pre : 0.2f * pre;

    float b = rule_b2[0];
    #pragma unroll 8
    for (int j = 0; j < 128; ++j) {
        float4 w = s_w1t[j];
        float2 bw = s_w12[j];
        float h = fmaf(rf.x, w.x, fmaf(rf.y, w.y, fmaf(rf.z, w.z, fmaf(rf.w, w.w, bw.x))));
        b = fmaf(fmaxf(h, 0.f), bw.y, b);
    }

    float gl = fmaf(rf.x, grw[0], fmaf(rf.y, grw[1],
               fmaf(rf.z, grw[2], fmaf(rf.w, grw[3], consts[1] + ss.y + dd.y))));
    float gamma = 1.f / (1.f + __expf(-gl));

    gamma_out[e] = gamma;
    b_out[e] = b;
    e_val[e] = e_base + gamma * b;
    atomicAdd(&deg[d], 1);
}

// fused single-block exclusive scan of deg -> rowPtr (+cursor copy)
__global__ void __launch_bounds__(1024) scan_kernel(
    const int* __restrict__ deg, int* __restrict__ rowPtr,
    int* __restrict__ cursor, int n, int n_edges)
{
    __shared__ int s[1024];
    int tid = threadIdx.x;
    int per = (n + 1023) >> 10;
    int lo = tid * per, hi = min(lo + per, n);
    int sum = 0;
    for (int i = lo; i < hi; ++i) sum += deg[i];
    s[tid] = sum;
    __syncthreads();
    for (int off = 1; off < 1024; off <<= 1) {
        int t = (tid >= off) ? s[tid - off] : 0;
        __syncthreads();
        s[tid] += t;
        __syncthreads();
    }
    int run = s[tid] - sum;  // exclusive prefix
    for (int i = lo; i < hi; ++i) {
        rowPtr[i] = run;
        cursor[i] = run;
        run += deg[i];
    }
    if (tid == 0) rowPtr[n] = n_edges;
}

// scatter 8B payload {e_val, src | type<<27} into CSR order
__global__ void __launch_bounds__(256) scatter_kernel(
    const int* __restrict__ ei, const int* __restrict__ et,
    const float* __restrict__ e_val, int* __restrict__ cursor,
    float2* __restrict__ payload, int n_edges)
{
    int e = blockIdx.x * blockDim.x + threadIdx.x;
    if (e >= n_edges) return;
    int d = ei[n_edges + e];
    int pos = atomicAdd(&cursor[d], 1);
    int st = ei[e] | (et[e] << 27);
    payload[pos] = make_float2(e_val[e], __int_as_float(st));
}

// one wave per dst node: coalesced payload, shuffle softmax, batch-4 gather.
__global__ void __launch_bounds__(256) gather_kernel(
    const int* __restrict__ rowPtr, const float2* __restrict__ payload,
    const unsigned* __restrict__ Vmb, const float* __restrict__ relM,
    float* __restrict__ out, float2* __restrict__ nodeMS, int n_nodes)
{
    int lane = threadIdx.x & 63;
    int d = blockIdx.x * 4 + (threadIdx.x >> 6);
    if (d >= n_nodes) return;
    int start = rowPtr[d];
    int deg = rowPtr[d + 1] - start;

    float acc0 = 0.f, acc1 = 0.f;
    float m = -INFINITY, inv;

    // batch-4 accumulation: 4 independent Vmb/relM loads in flight
    auto acc4 = [&](float av, int st, int k, int cnt) {
        float a[4];
        int s[4];
        #pragma unroll
        for (int i = 0; i < 4; ++i) {
            a[i] = __shfl(av, k + i, 64);   // padded lanes carry av=0
            s[i] = __shfl(st, k + i, 64);
        }
        unsigned v[4];
        float2 rm[4];
        #pragma unroll
        for (int i = 0; i < 4; ++i) {
            int ss = s[i] & 0x7FFFFFF;
            int tt = ((unsigned)s[i]) >> 27;
            v[i]  = Vmb[ss * 64 + lane];
            rm[i] = *(const float2*)&relM[tt * 128 + lane * 2];
        }
        #pragma unroll
        for (int i = 0; i < 4; ++i) {
            acc0 = fmaf(a[i], bflo(v[i]) + rm[i].x, acc0);
            acc1 = fmaf(a[i], bfhi(v[i]) + rm[i].y, acc1);
        }
    };

    if (deg <= 64) {
        float ev = -INFINITY;
        int st = 0;
        if (lane < deg) {
            float2 p = payload[start + lane];
            ev = p.x;
            st = __float_as_int(p.y);
        }
        m = wave_max(ev);
        float ex = (lane < deg) ? __expf(ev - m) : 0.f;
        float sum = wave_sum(ex);
        inv = 1.f / (sum + 1e-16f);
        float av = ex * inv;                 // 0 in padded lanes
        for (int k = 0; k < deg; k += 4) acc4(av, st, k, deg);
    } else {
        for (int i = lane; i < deg; i += 64) m = fmaxf(m, payload[start + i].x);
        m = wave_max(m);
        float sum = 0.f;
        for (int i = lane; i < deg; i += 64) sum += __expf(payload[start + i].x - m);
        sum = wave_sum(sum);
        inv = 1.f / (sum + 1e-16f);
        for (int c = 0; c < deg; c += 64) {
            int i = c + lane;
            float av = 0.f;
            int st = 0;
            if (i < deg) {
                float2 p = payload[start + i];
                av = __expf(p.x - m) * inv;
                st = __float_as_int(p.y);
            }
            int cnt = min(64, deg - c);
            for (int k = 0; k < cnt; k += 4) acc4(av, st, k, cnt);
        }
    }
    if (lane == 0) nodeMS[d] = make_float2(m, inv);
    *(float2*)&out[d * 128 + lane * 2] = make_float2(acc0, acc1);
}

// fully-coalesced alpha: alpha[e] = exp(e_val[e] - m[d]) * inv[d]
__global__ void __launch_bounds__(256) alpha_kernel(
    const int* __restrict__ ei, const float* __restrict__ e_val,
    const float2* __restrict__ nodeMS, float* __restrict__ alpha_out, int n_edges)
{
    int e = blockIdx.x * blockDim.x + threadIdx.x;
    if (e >= n_edges) return;
    int d = ei[n_edges + e];
    float2 ms = nodeMS[d];
    alpha_out[e] = __expf(e_val[e] - ms.x) * ms.y;
}

extern "C" void kernel_launch(void* const* d_in, const int* in_sizes, int n_in,
                              void* d_out, int out_size, void* d_ws, size_t ws_size,
                              hipStream_t stream)
{
    const float* x        = (const float*)d_in[0];
    const int*   ei       = (const int*)d_in[1];
    const int*   et       = (const int*)d_in[2];
    const float* erf      = (const float*)d_in[3];
    const float* Wq       = (const float*)d_in[5];
    const float* bq       = (const float*)d_in[6];
    const float* Wk       = (const float*)d_in[7];
    const float* bk       = (const float*)d_in[8];
    const float* Wv       = (const float*)d_in[9];
    const float* bv       = (const float*)d_in[10];
    const float* rel_emb  = (const float*)d_in[11];
    const float* attn_vec = (const float*)d_in[12];
    const float* rule_w1  = (const float*)d_in[13];
    const float* rule_b1  = (const float*)d_in[14];
    const float* rule_w2  = (const float*)d_in[15];
    const float* rule_b2  = (const float*)d_in[16];
    const float* grw      = (const float*)d_in[17];
    const float* grb      = (const float*)d_in[18];
    const float* gnw      = (const float*)d_in[19];
    const float* gnb      = (const float*)d_in[20];
    const float* msg_w    = (const float*)d_in[21];
    const float* msg_b    = (const float*)d_in[22];

    const int n_nodes = in_sizes[0] / 128;
    const int n_edges = in_sizes[2];

    float* ws = (float*)d_ws;
    size_t off = 0;
    unsigned* Vmb  = (unsigned*)(ws + off); off += (size_t)n_nodes * 64;
    float2* payload = (float2*)(ws + off); off += 2 * (size_t)n_edges;
    float* e_val   = ws + off; off += n_edges;
    float* srcPack = ws + off; off += 2 * (size_t)n_nodes;
    float* dstPack = ws + off; off += 2 * (size_t)n_nodes;
    float2* nodeMS = (float2*)(ws + off); off += 2 * (size_t)n_nodes;
    int*   deg     = (int*)(ws + off); off += n_nodes;        // reused as cursor
    int*   rowPtr  = (int*)(ws + off); off += n_nodes + 4;
    unsigned short* W2b = (unsigned short*)(ws + off); off += 128 * 64;  // 16384 shorts
    float* c2      = ws + off; off += 128;
    float* wkA     = ws + off; off += 128;
    float* wqA     = ws + off; off += 128;
    float* wkG     = ws + off; off += 128;
    float* wqG     = ws + off; off += 128;
    float* relA    = ws + off; off += 16;
    float* relM    = ws + off; off += 16 * 128;
    float* consts  = ws + off; off += 2;
    off += 2;  // 16B alignment for w1t
    float4* w1t    = (float4*)(ws + off); off += 128 * 4;
    float2* w12    = (float2*)(ws + off); off += 128 * 2;

    float* out       = (float*)d_out;
    float* alpha_out = out + (size_t)n_nodes * 128;
    float* gamma_out = alpha_out + n_edges;
    float* b_out     = gamma_out + n_edges;

    hipLaunchKernelGGL(precompute_kernel, dim3(146), dim3(128), 0, stream,
                       Wq, bq, Wk, bk, Wv, bv, rel_emb, attn_vec, msg_w, msg_b,
                       gnw, grb, gnb, rule_w1, rule_b1, rule_w2,
                       W2b, c2, wkA, wqA, wkG, wqG, relA, relM, consts, w1t, w12);

    hipLaunchKernelGGL(node_kernel, dim3((n_nodes + 127) / 128), dim3(256), 0, stream,
                       (const float4*)x, W2b, c2,
                       wkA, wqA, wkG, wqG, Vmb, (float2*)srcPack, (float2*)dstPack,
                       deg, n_nodes);

    hipLaunchKernelGGL(edge1_kernel, dim3((n_edges + 255) / 256), dim3(256), 0, stream,
                       ei, et, (const float4*)erf, (const float4*)w1t, (const float2*)w12,
                       rule_b2, grw, (const float2*)srcPack, (const float2*)dstPack,
                       relA, consts, e_val, gamma_out, b_out, deg, n_edges);

    hipLaunchKernelGGL(scan_kernel, dim3(1), dim3(1024), 0, stream,
                       deg, rowPtr, deg /*cursor (in-place ok: rewritten)*/,
                       n_nodes, n_edges);

    hipLaunchKernelGGL(scatter_kernel, dim3((n_edges + 255) / 256), dim3(256), 0, stream,
                       ei, et, e_val, deg /*cursor*/, payload, n_edges);

    hipLaunchKernelGGL(gather_kernel, dim3((n_nodes + 3) / 4), dim3(256), 0, stream,
                       rowPtr, payload, Vmb, relM, out, nodeMS, n_nodes);

    hipLaunchKernelGGL(alpha_kernel, dim3((n_edges + 255) / 256), dim3(256), 0, stream,
                       ei, e_val, nodeMS, alpha_out, n_edges);
}

// Round 6
// 325.481 us; speedup vs baseline: 1.3009x; 1.3009x over previous
//
#include <hip/hip_runtime.h>
#include <math.h>

// ---------------------------------------------------------------------------
// RGAPConv, CSR-gather formulation (R6 = R5 with hierarchical 3-launch scan):
//   node:      tiled GEMM with bf16 LDS tiles (68 KB -> 2 blocks/CU, 1 round);
//              fp32 scalar packs from global x; Vm emitted packed bf16.
//   edge1:     e_val/gamma/b + dst histogram.
//   CSR build: scan1/scan2/scan3 (parallel) -> scatter 8B payload.
//   gather:    one wave per dst node, shuffle softmax, batch-4 unrolled
//              accumulation. alpha via coalesced kernel.
// ---------------------------------------------------------------------------

__device__ __forceinline__ float wave_max(float v) {
    #pragma unroll
    for (int o = 32; o > 0; o >>= 1) v = fmaxf(v, __shfl_xor(v, o, 64));
    return v;
}
__device__ __forceinline__ float wave_sum(float v) {
    #pragma unroll
    for (int o = 32; o > 0; o >>= 1) v += __shfl_xor(v, o, 64);
    return v;
}

__device__ __forceinline__ unsigned bf16rne(float f) {
    unsigned u = __float_as_uint(f);
    return (u + 0x7FFFu + ((u >> 16) & 1u)) >> 16;  // round-to-nearest-even
}
__device__ __forceinline__ float bflo(unsigned u) { return __uint_as_float(u << 16); }
__device__ __forceinline__ float bfhi(unsigned u) { return __uint_as_float(u & 0xFFFF0000u); }

// grid = 146 blocks x 128 threads. Builds all small tables.
__global__ void __launch_bounds__(128) precompute_kernel(
    const float* __restrict__ Wq, const float* __restrict__ bq,
    const float* __restrict__ Wk, const float* __restrict__ bk,
    const float* __restrict__ Wv, const float* __restrict__ bv,
    const float* __restrict__ rel_emb, const float* __restrict__ attn_vec,
    const float* __restrict__ msg_w, const float* __restrict__ msg_b,
    const float* __restrict__ gnw, const float* __restrict__ grb,
    const float* __restrict__ gnb,
    const float* __restrict__ rule_w1, const float* __restrict__ rule_b1,
    const float* __restrict__ rule_w2,
    unsigned short* __restrict__ W2b, float* __restrict__ c2,
    float* __restrict__ wkA, float* __restrict__ wqA,
    float* __restrict__ wkG, float* __restrict__ wqG,
    float* __restrict__ relA, float* __restrict__ relM,
    float* __restrict__ consts,
    float4* __restrict__ w1t, float2* __restrict__ w12)
{
    __shared__ float red[128];
    int bid = blockIdx.x, j = threadIdx.x;

    auto blk_reduce = [&](float v) -> float {
        red[j] = v;
        __syncthreads();
        for (int s = 64; s > 0; s >>= 1) {
            if (j < s) red[j] += red[j + s];
            __syncthreads();
        }
        float r = red[0];
        __syncthreads();
        return r;
    };

    if (bid < 128) {
        int i = bid;
        float acc = 0.f;
        #pragma unroll 8
        for (int k = 0; k < 128; ++k) acc = fmaf(Wv[i * 128 + k], msg_w[k * 128 + j], acc);
        W2b[i * 128 + j] = (unsigned short)bf16rne(acc);
        float r;
        r = blk_reduce(Wk[i * 128 + j] * attn_vec[j]);        if (j == 0) wkA[i] = r;
        r = blk_reduce(Wq[i * 128 + j] * attn_vec[128 + j]);  if (j == 0) wqA[i] = r;
        r = blk_reduce(Wk[i * 128 + j] * gnw[j]);             if (j == 0) wkG[i] = r;
        r = blk_reduce(Wq[i * 128 + j] * gnw[128 + j]);       if (j == 0) wqG[i] = r;
    } else if (bid < 144) {
        int t = bid - 128;
        float acc = 0.f;
        #pragma unroll 8
        for (int k = 0; k < 128; ++k) acc = fmaf(rel_emb[t * 128 + k], msg_w[k * 128 + j], acc);
        relM[t * 128 + j] = acc;
        float r = blk_reduce(rel_emb[t * 128 + j] * attn_vec[256 + j]);
        if (j == 0) relA[t] = r;
    } else if (bid == 144) {
        float acc = msg_b[j];
        #pragma unroll 8
        for (int k = 0; k < 128; ++k) acc = fmaf(bv[k], msg_w[k * 128 + j], acc);
        c2[j] = acc;
        w1t[j] = make_float4(rule_w1[j], rule_w1[128 + j], rule_w1[256 + j], rule_w1[384 + j]);
        w12[j] = make_float2(rule_b1[j], rule_w2[j]);
    } else {
        float r = blk_reduce(bk[j] * attn_vec[j] + bq[j] * attn_vec[128 + j]);
        if (j == 0) consts[0] = r;
        r = blk_reduce(bk[j] * gnw[j] + bq[j] * gnw[128 + j]);
        if (j == 0) consts[1] = r + grb[0] + gnb[0];
    }
}

// Tiled GEMM, bf16 LDS tiles: 128 rows x 128 cols per block, K=128 resident.
__global__ void __launch_bounds__(256) node_kernel(
    const float4* __restrict__ x4, const unsigned short* __restrict__ W2b,
    const float* __restrict__ c2,
    const float* __restrict__ wkA, const float* __restrict__ wqA,
    const float* __restrict__ wkG, const float* __restrict__ wqG,
    unsigned* __restrict__ Vmb, float2* __restrict__ srcPack,
    float2* __restrict__ dstPack, int* __restrict__ deg, int n_nodes)
{
    __shared__ unsigned short Asu[128][136];
    __shared__ unsigned short Bsu[128][136];
    const int tid = threadIdx.x;
    const int rowBase = blockIdx.x * 128;

    if (tid < 128 && rowBase + tid < n_nodes) deg[rowBase + tid] = 0;

    #pragma unroll
    for (int l = 0; l < 16; ++l) {
        int flat = l * 256 + tid;        // 4096 quads
        int k = flat >> 5, n4 = flat & 31;
        uint2 w = *(const uint2*)&W2b[k * 128 + n4 * 4];
        *(uint2*)&Bsu[k][n4 * 4] = w;
    }
    #pragma unroll
    for (int l = 0; l < 16; ++l) {
        int flat = l * 256 + tid;
        int r = flat & 127;
        int k4 = flat >> 7;
        int row = rowBase + r;
        float4 v = (row < n_nodes) ? x4[row * 32 + k4] : make_float4(0.f, 0.f, 0.f, 0.f);
        Asu[4 * k4 + 0][r] = (unsigned short)bf16rne(v.x);
        Asu[4 * k4 + 1][r] = (unsigned short)bf16rne(v.y);
        Asu[4 * k4 + 2][r] = (unsigned short)bf16rne(v.z);
        Asu[4 * k4 + 3][r] = (unsigned short)bf16rne(v.w);
    }

    // fp32 per-node scalar packs from global x (L2-hot after staging)
    {
        int r = tid & 127, h = tid >> 7;
        int row = rowBase + r;
        if (row < n_nodes) {
            const float4* wa4 = (const float4*)(h ? wqA : wkA);
            const float4* wg4 = (const float4*)(h ? wqG : wkG);
            float sA = 0.f, sG = 0.f;
            #pragma unroll 8
            for (int k4 = 0; k4 < 32; ++k4) {
                float4 xv = x4[row * 32 + k4];
                float4 wa = wa4[k4], wg = wg4[k4];
                sA = fmaf(xv.x, wa.x, fmaf(xv.y, wa.y, fmaf(xv.z, wa.z, fmaf(xv.w, wa.w, sA))));
                sG = fmaf(xv.x, wg.x, fmaf(xv.y, wg.y, fmaf(xv.z, wg.z, fmaf(xv.w, wg.w, sG))));
            }
            if (h) dstPack[row] = make_float2(sA, sG);
            else   srcPack[row] = make_float2(sA, sG);
        }
    }
    __syncthreads();

    const int tx = tid & 15, ty = tid >> 4;
    float acc[8][8];
    #pragma unroll
    for (int i = 0; i < 8; ++i)
        #pragma unroll
        for (int j = 0; j < 8; ++j) acc[i][j] = 0.f;

    #pragma unroll 2
    for (int k = 0; k < 128; ++k) {
        uint4 au = *(const uint4*)&Asu[k][ty * 8];
        uint4 bu = *(const uint4*)&Bsu[k][tx * 8];
        float a[8] = {bflo(au.x), bfhi(au.x), bflo(au.y), bfhi(au.y),
                      bflo(au.z), bfhi(au.z), bflo(au.w), bfhi(au.w)};
        float b[8] = {bflo(bu.x), bfhi(bu.x), bflo(bu.y), bfhi(bu.y),
                      bflo(bu.z), bfhi(bu.z), bflo(bu.w), bfhi(bu.w)};
        #pragma unroll
        for (int i = 0; i < 8; ++i)
            #pragma unroll
            for (int j = 0; j < 8; ++j)
                acc[i][j] = fmaf(a[i], b[j], acc[i][j]);
    }

    float c2v[8];
    #pragma unroll
    for (int j = 0; j < 8; ++j) c2v[j] = c2[tx * 8 + j];
    #pragma unroll
    for (int i = 0; i < 8; ++i) {
        int row = rowBase + ty * 8 + i;
        if (row < n_nodes) {
            uint4 o;
            o.x = bf16rne(acc[i][0] + c2v[0]) | (bf16rne(acc[i][1] + c2v[1]) << 16);
            o.y = bf16rne(acc[i][2] + c2v[2]) | (bf16rne(acc[i][3] + c2v[3]) << 16);
            o.z = bf16rne(acc[i][4] + c2v[4]) | (bf16rne(acc[i][5] + c2v[5]) << 16);
            o.w = bf16rne(acc[i][6] + c2v[6]) | (bf16rne(acc[i][7] + c2v[7]) << 16);
            *(uint4*)&Vmb[row * 64 + tx * 4] = o;
        }
    }
}

// one thread per edge: e_val, gamma, b + deg histogram
__global__ void __launch_bounds__(256) edge1_kernel(
    const int* __restrict__ ei, const int* __restrict__ et,
    const float4* __restrict__ erf,
    const float4* __restrict__ w1t, const float2* __restrict__ w12,
    const float* __restrict__ rule_b2, const float* __restrict__ grw,
    const float2* __restrict__ srcPack, const float2* __restrict__ dstPack,
    const float* __restrict__ relA, const float* __restrict__ consts,
    float* __restrict__ e_val, float* __restrict__ gamma_out,
    float* __restrict__ b_out, int* __restrict__ deg,
    int n_edges)
{
    __shared__ float4 s_w1t[128];
    __shared__ float2 s_w12[128];
    int tid = threadIdx.x;
    if (tid < 128) { s_w1t[tid] = w1t[tid]; s_w12[tid] = w12[tid]; }
    __syncthreads();
    int e = blockIdx.x * 256 + tid;
    if (e >= n_edges) return;

    int s = ei[e], d = ei[n_edges + e], t = et[e];
    float4 rf = erf[e];
    float2 ss = srcPack[s], dd = dstPack[d];

    float pre = ss.x + dd.x + relA[t] + consts[0];
    float e_base = pre >= 0.f ? pre : 0.2f * pre;

    float b = rule_b2[0];
    #pragma unroll 8
    for (int j = 0; j < 128; ++j) {
        float4 w = s_w1t[j];
        float2 bw = s_w12[j];
        float h = fmaf(rf.x, w.x, fmaf(rf.y, w.y, fmaf(rf.z, w.z, fmaf(rf.w, w.w, bw.x))));
        b = fmaf(fmaxf(h, 0.f), bw.y, b);
    }

    float gl = fmaf(rf.x, grw[0], fmaf(rf.y, grw[1],
               fmaf(rf.z, grw[2], fmaf(rf.w, grw[3], consts[1] + ss.y + dd.y))));
    float gamma = 1.f / (1.f + __expf(-gl));

    gamma_out[e] = gamma;
    b_out[e] = b;
    e_val[e] = e_base + gamma * b;
    atomicAdd(&deg[d], 1);
}

// ---- CSR build: hierarchical scan of deg -> rowPtr ----
__global__ void __launch_bounds__(256) scan1_kernel(
    const int* __restrict__ deg, int* __restrict__ rowPtr,
    int* __restrict__ partials, int n)
{
    __shared__ int sdata[256];
    int tid = threadIdx.x;
    int base = blockIdx.x * 1024 + tid * 4;
    int v0 = (base + 0 < n) ? deg[base + 0] : 0;
    int v1 = (base + 1 < n) ? deg[base + 1] : 0;
    int v2 = (base + 2 < n) ? deg[base + 2] : 0;
    int v3 = (base + 3 < n) ? deg[base + 3] : 0;
    int tsum = v0 + v1 + v2 + v3;
    sdata[tid] = tsum;
    __syncthreads();
    #pragma unroll
    for (int off = 1; off < 256; off <<= 1) {
        int t = (tid >= off) ? sdata[tid - off] : 0;
        __syncthreads();
        sdata[tid] += t;
        __syncthreads();
    }
    int excl = sdata[tid] - tsum;
    if (base + 0 < n) rowPtr[base + 0] = excl;
    if (base + 1 < n) rowPtr[base + 1] = excl + v0;
    if (base + 2 < n) rowPtr[base + 2] = excl + v0 + v1;
    if (base + 3 < n) rowPtr[base + 3] = excl + v0 + v1 + v2;
    if (tid == 255) partials[blockIdx.x] = sdata[255];
}

__global__ void __launch_bounds__(64) scan2_kernel(int* __restrict__ partials, int nb)
{
    int lane = threadIdx.x;
    int v = (lane < nb) ? partials[lane] : 0;
    int orig = v;
    #pragma unroll
    for (int off = 1; off < 64; off <<= 1) {
        int t = __shfl_up(v, off, 64);
        if (lane >= off) v += t;
    }
    if (lane < nb) partials[lane] = v - orig;
}

__global__ void __launch_bounds__(256) scan3_kernel(
    int* __restrict__ rowPtr, const int* __restrict__ partials,
    int* __restrict__ cursor, int n, int n_edges)
{
    int off = partials[blockIdx.x];
    int base = blockIdx.x * 1024 + threadIdx.x * 4;
    #pragma unroll
    for (int k = 0; k < 4; ++k) {
        int idx = base + k;
        if (idx < n) {
            int r = rowPtr[idx] + off;
            rowPtr[idx] = r;
            cursor[idx] = r;
        }
    }
    if (blockIdx.x == 0 && threadIdx.x == 0) rowPtr[n] = n_edges;
}

// scatter 8B payload {e_val, src | type<<27} into CSR order
__global__ void __launch_bounds__(256) scatter_kernel(
    const int* __restrict__ ei, const int* __restrict__ et,
    const float* __restrict__ e_val, int* __restrict__ cursor,
    float2* __restrict__ payload, int n_edges)
{
    int e = blockIdx.x * blockDim.x + threadIdx.x;
    if (e >= n_edges) return;
    int d = ei[n_edges + e];
    int pos = atomicAdd(&cursor[d], 1);
    int st = ei[e] | (et[e] << 27);
    payload[pos] = make_float2(e_val[e], __int_as_float(st));
}

// one wave per dst node: coalesced payload, shuffle softmax, batch-4 gather.
__global__ void __launch_bounds__(256) gather_kernel(
    const int* __restrict__ rowPtr, const float2* __restrict__ payload,
    const unsigned* __restrict__ Vmb, const float* __restrict__ relM,
    float* __restrict__ out, float2* __restrict__ nodeMS, int n_nodes)
{
    int lane = threadIdx.x & 63;
    int d = blockIdx.x * 4 + (threadIdx.x >> 6);
    if (d >= n_nodes) return;
    int start = rowPtr[d];
    int deg = rowPtr[d + 1] - start;

    float acc0 = 0.f, acc1 = 0.f;
    float m = -INFINITY, inv;

    // batch-4 accumulation: 4 independent Vmb/relM loads in flight
    auto acc4 = [&](float av, int st, int k) {
        float a[4];
        int s[4];
        #pragma unroll
        for (int i = 0; i < 4; ++i) {
            a[i] = __shfl(av, k + i, 64);   // padded lanes carry av=0
            s[i] = __shfl(st, k + i, 64);
        }
        unsigned v[4];
        float2 rm[4];
        #pragma unroll
        for (int i = 0; i < 4; ++i) {
            int ss = s[i] & 0x7FFFFFF;
            int tt = ((unsigned)s[i]) >> 27;
            v[i]  = Vmb[ss * 64 + lane];
            rm[i] = *(const float2*)&relM[tt * 128 + lane * 2];
        }
        #pragma unroll
        for (int i = 0; i < 4; ++i) {
            acc0 = fmaf(a[i], bflo(v[i]) + rm[i].x, acc0);
            acc1 = fmaf(a[i], bfhi(v[i]) + rm[i].y, acc1);
        }
    };

    if (deg <= 64) {
        float ev = -INFINITY;
        int st = 0;
        if (lane < deg) {
            float2 p = payload[start + lane];
            ev = p.x;
            st = __float_as_int(p.y);
        }
        m = wave_max(ev);
        float ex = (lane < deg) ? __expf(ev - m) : 0.f;
        float sum = wave_sum(ex);
        inv = 1.f / (sum + 1e-16f);
        float av = ex * inv;                 // 0 in padded lanes
        for (int k = 0; k < deg; k += 4) acc4(av, st, k);
    } else {
        for (int i = lane; i < deg; i += 64) m = fmaxf(m, payload[start + i].x);
        m = wave_max(m);
        float sum = 0.f;
        for (int i = lane; i < deg; i += 64) sum += __expf(payload[start + i].x - m);
        sum = wave_sum(sum);
        inv = 1.f / (sum + 1e-16f);
        for (int c = 0; c < deg; c += 64) {
            int i = c + lane;
            float av = 0.f;
            int st = 0;
            if (i < deg) {
                float2 p = payload[start + i];
                av = __expf(p.x - m) * inv;
                st = __float_as_int(p.y);
            }
            int cnt = min(64, deg - c);
            for (int k = 0; k < cnt; k += 4) acc4(av, st, k);
        }
    }
    if (lane == 0) nodeMS[d] = make_float2(m, inv);
    *(float2*)&out[d * 128 + lane * 2] = make_float2(acc0, acc1);
}

// fully-coalesced alpha: alpha[e] = exp(e_val[e] - m[d]) * inv[d]
__global__ void __launch_bounds__(256) alpha_kernel(
    const int* __restrict__ ei, const float* __restrict__ e_val,
    const float2* __restrict__ nodeMS, float* __restrict__ alpha_out, int n_edges)
{
    int e = blockIdx.x * blockDim.x + threadIdx.x;
    if (e >= n_edges) return;
    int d = ei[n_edges + e];
    float2 ms = nodeMS[d];
    alpha_out[e] = __expf(e_val[e] - ms.x) * ms.y;
}

extern "C" void kernel_launch(void* const* d_in, const int* in_sizes, int n_in,
                              void* d_out, int out_size, void* d_ws, size_t ws_size,
                              hipStream_t stream)
{
    const float* x        = (const float*)d_in[0];
    const int*   ei       = (const int*)d_in[1];
    const int*   et       = (const int*)d_in[2];
    const float* erf      = (const float*)d_in[3];
    const float* Wq       = (const float*)d_in[5];
    const float* bq       = (const float*)d_in[6];
    const float* Wk       = (const float*)d_in[7];
    const float* bk       = (const float*)d_in[8];
    const float* Wv       = (const float*)d_in[9];
    const float* bv       = (const float*)d_in[10];
    const float* rel_emb  = (const float*)d_in[11];
    const float* attn_vec = (const float*)d_in[12];
    const float* rule_w1  = (const float*)d_in[13];
    const float* rule_b1  = (const float*)d_in[14];
    const float* rule_w2  = (const float*)d_in[15];
    const float* rule_b2  = (const float*)d_in[16];
    const float* grw      = (const float*)d_in[17];
    const float* grb      = (const float*)d_in[18];
    const float* gnw      = (const float*)d_in[19];
    const float* gnb      = (const float*)d_in[20];
    const float* msg_w    = (const float*)d_in[21];
    const float* msg_b    = (const float*)d_in[22];

    const int n_nodes = in_sizes[0] / 128;
    const int n_edges = in_sizes[2];
    const int nb = (n_nodes + 1023) / 1024;  // scan blocks (<= 64 required)

    float* ws = (float*)d_ws;
    size_t off = 0;
    unsigned* Vmb  = (unsigned*)(ws + off); off += (size_t)n_nodes * 64;
    float2* payload = (float2*)(ws + off); off += 2 * (size_t)n_edges;
    float* e_val   = ws + off; off += n_edges;
    float* srcPack = ws + off; off += 2 * (size_t)n_nodes;
    float* dstPack = ws + off; off += 2 * (size_t)n_nodes;
    float2* nodeMS = (float2*)(ws + off); off += 2 * (size_t)n_nodes;
    int*   deg     = (int*)(ws + off); off += n_nodes;        // reused as cursor
    int*   rowPtr  = (int*)(ws + off); off += n_nodes + 4;
    int*   partials= (int*)(ws + off); off += 64;
    unsigned short* W2b = (unsigned short*)(ws + off); off += 128 * 64;
    float* c2      = ws + off; off += 128;
    float* wkA     = ws + off; off += 128;
    float* wqA     = ws + off; off += 128;
    float* wkG     = ws + off; off += 128;
    float* wqG     = ws + off; off += 128;
    float* relA    = ws + off; off += 16;
    float* relM    = ws + off; off += 16 * 128;
    float* consts  = ws + off; off += 2;
    off += 2;  // 16B alignment for w1t
    float4* w1t    = (float4*)(ws + off); off += 128 * 4;
    float2* w12    = (float2*)(ws + off); off += 128 * 2;

    float* out       = (float*)d_out;
    float* alpha_out = out + (size_t)n_nodes * 128;
    float* gamma_out = alpha_out + n_edges;
    float* b_out     = gamma_out + n_edges;

    hipLaunchKernelGGL(precompute_kernel, dim3(146), dim3(128), 0, stream,
                       Wq, bq, Wk, bk, Wv, bv, rel_emb, attn_vec, msg_w, msg_b,
                       gnw, grb, gnb, rule_w1, rule_b1, rule_w2,
                       W2b, c2, wkA, wqA, wkG, wqG, relA, relM, consts, w1t, w12);

    hipLaunchKernelGGL(node_kernel, dim3((n_nodes + 127) / 128), dim3(256), 0, stream,
                       (const float4*)x, W2b, c2,
                       wkA, wqA, wkG, wqG, Vmb, (float2*)srcPack, (float2*)dstPack,
                       deg, n_nodes);

    hipLaunchKernelGGL(edge1_kernel, dim3((n_edges + 255) / 256), dim3(256), 0, stream,
                       ei, et, (const float4*)erf, (const float4*)w1t, (const float2*)w12,
                       rule_b2, grw, (const float2*)srcPack, (const float2*)dstPack,
                       relA, consts, e_val, gamma_out, b_out, deg, n_edges);

    hipLaunchKernelGGL(scan1_kernel, dim3(nb), dim3(256), 0, stream,
                       deg, rowPtr, partials, n_nodes);
    hipLaunchKernelGGL(scan2_kernel, dim3(1), dim3(64), 0, stream,
                       partials, nb);
    hipLaunchKernelGGL(scan3_kernel, dim3(nb), dim3(256), 0, stream,
                       rowPtr, partials, deg /*cursor*/, n_nodes, n_edges);

    hipLaunchKernelGGL(scatter_kernel, dim3((n_edges + 255) / 256), dim3(256), 0, stream,
                       ei, et, e_val, deg /*cursor*/, payload, n_edges);

    hipLaunchKernelGGL(gather_kernel, dim3((n_nodes + 3) / 4), dim3(256), 0, stream,
                       rowPtr, payload, Vmb, relM, out, nodeMS, n_nodes);

    hipLaunchKernelGGL(alpha_kernel, dim3((n_edges + 255) / 256), dim3(256), 0, stream,
                       ei, e_val, nodeMS, alpha_out, n_edges);
}

// Round 7
// 296.035 us; speedup vs baseline: 1.4303x; 1.0995x over previous
//
#include <hip/hip_runtime.h>
#include <math.h>

// ---------------------------------------------------------------------------
// RGAPConv, CSR-gather formulation (R7 = R6 with 2-phase counting-sort CSR):
//   node:      tiled GEMM with bf16 LDS tiles; fp32 scalar packs; Vm bf16.
//   edge1:     e_val/gamma/b + dst histogram.
//   CSR build: scan1/scan2/scan3 -> sort1 (LDS-binned coarse scatter, buckets
//              of 256 dsts, coalesced runs) -> sort2 (per-bucket exact CSR
//              placement via LDS cursors, writes stay in a 32KB L2 window).
//   gather:    one wave per dst node, shuffle softmax, batch-4 accumulation.
//   alpha:     coalesced per-edge kernel from per-node {m, inv}.
// ---------------------------------------------------------------------------

__device__ __forceinline__ float wave_max(float v) {
    #pragma unroll
    for (int o = 32; o > 0; o >>= 1) v = fmaxf(v, __shfl_xor(v, o, 64));
    return v;
}
__device__ __forceinline__ float wave_sum(float v) {
    #pragma unroll
    for (int o = 32; o > 0; o >>= 1) v += __shfl_xor(v, o, 64);
    return v;
}

__device__ __forceinline__ unsigned bf16rne(float f) {
    unsigned u = __float_as_uint(f);
    return (u + 0x7FFFu + ((u >> 16) & 1u)) >> 16;  // round-to-nearest-even
}
__device__ __forceinline__ float bflo(unsigned u) { return __uint_as_float(u << 16); }
__device__ __forceinline__ float bfhi(unsigned u) { return __uint_as_float(u & 0xFFFF0000u); }

// grid = 146 blocks x 128 threads. Builds all small tables.
__global__ void __launch_bounds__(128) precompute_kernel(
    const float* __restrict__ Wq, const float* __restrict__ bq,
    const float* __restrict__ Wk, const float* __restrict__ bk,
    const float* __restrict__ Wv, const float* __restrict__ bv,
    const float* __restrict__ rel_emb, const float* __restrict__ attn_vec,
    const float* __restrict__ msg_w, const float* __restrict__ msg_b,
    const float* __restrict__ gnw, const float* __restrict__ grb,
    const float* __restrict__ gnb,
    const float* __restrict__ rule_w1, const float* __restrict__ rule_b1,
    const float* __restrict__ rule_w2,
    unsigned short* __restrict__ W2b, float* __restrict__ c2,
    float* __restrict__ wkA, float* __restrict__ wqA,
    float* __restrict__ wkG, float* __restrict__ wqG,
    float* __restrict__ relA, float* __restrict__ relM,
    float* __restrict__ consts,
    float4* __restrict__ w1t, float2* __restrict__ w12)
{
    __shared__ float red[128];
    int bid = blockIdx.x, j = threadIdx.x;

    auto blk_reduce = [&](float v) -> float {
        red[j] = v;
        __syncthreads();
        for (int s = 64; s > 0; s >>= 1) {
            if (j < s) red[j] += red[j + s];
            __syncthreads();
        }
        float r = red[0];
        __syncthreads();
        return r;
    };

    if (bid < 128) {
        int i = bid;
        float acc = 0.f;
        #pragma unroll 8
        for (int k = 0; k < 128; ++k) acc = fmaf(Wv[i * 128 + k], msg_w[k * 128 + j], acc);
        W2b[i * 128 + j] = (unsigned short)bf16rne(acc);
        float r;
        r = blk_reduce(Wk[i * 128 + j] * attn_vec[j]);        if (j == 0) wkA[i] = r;
        r = blk_reduce(Wq[i * 128 + j] * attn_vec[128 + j]);  if (j == 0) wqA[i] = r;
        r = blk_reduce(Wk[i * 128 + j] * gnw[j]);             if (j == 0) wkG[i] = r;
        r = blk_reduce(Wq[i * 128 + j] * gnw[128 + j]);       if (j == 0) wqG[i] = r;
    } else if (bid < 144) {
        int t = bid - 128;
        float acc = 0.f;
        #pragma unroll 8
        for (int k = 0; k < 128; ++k) acc = fmaf(rel_emb[t * 128 + k], msg_w[k * 128 + j], acc);
        relM[t * 128 + j] = acc;
        float r = blk_reduce(rel_emb[t * 128 + j] * attn_vec[256 + j]);
        if (j == 0) relA[t] = r;
    } else if (bid == 144) {
        float acc = msg_b[j];
        #pragma unroll 8
        for (int k = 0; k < 128; ++k) acc = fmaf(bv[k], msg_w[k * 128 + j], acc);
        c2[j] = acc;
        w1t[j] = make_float4(rule_w1[j], rule_w1[128 + j], rule_w1[256 + j], rule_w1[384 + j]);
        w12[j] = make_float2(rule_b1[j], rule_w2[j]);
    } else {
        float r = blk_reduce(bk[j] * attn_vec[j] + bq[j] * attn_vec[128 + j]);
        if (j == 0) consts[0] = r;
        r = blk_reduce(bk[j] * gnw[j] + bq[j] * gnw[128 + j]);
        if (j == 0) consts[1] = r + grb[0] + gnb[0];
    }
}

// Tiled GEMM, bf16 LDS tiles: 128 rows x 128 cols per block, K=128 resident.
__global__ void __launch_bounds__(256) node_kernel(
    const float4* __restrict__ x4, const unsigned short* __restrict__ W2b,
    const float* __restrict__ c2,
    const float* __restrict__ wkA, const float* __restrict__ wqA,
    const float* __restrict__ wkG, const float* __restrict__ wqG,
    unsigned* __restrict__ Vmb, float2* __restrict__ srcPack,
    float2* __restrict__ dstPack, int* __restrict__ deg, int n_nodes)
{
    __shared__ unsigned short Asu[128][136];
    __shared__ unsigned short Bsu[128][136];
    const int tid = threadIdx.x;
    const int rowBase = blockIdx.x * 128;

    if (tid < 128 && rowBase + tid < n_nodes) deg[rowBase + tid] = 0;

    #pragma unroll
    for (int l = 0; l < 16; ++l) {
        int flat = l * 256 + tid;        // 4096 quads
        int k = flat >> 5, n4 = flat & 31;
        uint2 w = *(const uint2*)&W2b[k * 128 + n4 * 4];
        *(uint2*)&Bsu[k][n4 * 4] = w;
    }
    #pragma unroll
    for (int l = 0; l < 16; ++l) {
        int flat = l * 256 + tid;
        int r = flat & 127;
        int k4 = flat >> 7;
        int row = rowBase + r;
        float4 v = (row < n_nodes) ? x4[row * 32 + k4] : make_float4(0.f, 0.f, 0.f, 0.f);
        Asu[4 * k4 + 0][r] = (unsigned short)bf16rne(v.x);
        Asu[4 * k4 + 1][r] = (unsigned short)bf16rne(v.y);
        Asu[4 * k4 + 2][r] = (unsigned short)bf16rne(v.z);
        Asu[4 * k4 + 3][r] = (unsigned short)bf16rne(v.w);
    }

    // fp32 per-node scalar packs from global x (L2-hot after staging)
    {
        int r = tid & 127, h = tid >> 7;
        int row = rowBase + r;
        if (row < n_nodes) {
            const float4* wa4 = (const float4*)(h ? wqA : wkA);
            const float4* wg4 = (const float4*)(h ? wqG : wkG);
            float sA = 0.f, sG = 0.f;
            #pragma unroll 8
            for (int k4 = 0; k4 < 32; ++k4) {
                float4 xv = x4[row * 32 + k4];
                float4 wa = wa4[k4], wg = wg4[k4];
                sA = fmaf(xv.x, wa.x, fmaf(xv.y, wa.y, fmaf(xv.z, wa.z, fmaf(xv.w, wa.w, sA))));
                sG = fmaf(xv.x, wg.x, fmaf(xv.y, wg.y, fmaf(xv.z, wg.z, fmaf(xv.w, wg.w, sG))));
            }
            if (h) dstPack[row] = make_float2(sA, sG);
            else   srcPack[row] = make_float2(sA, sG);
        }
    }
    __syncthreads();

    const int tx = tid & 15, ty = tid >> 4;
    float acc[8][8];
    #pragma unroll
    for (int i = 0; i < 8; ++i)
        #pragma unroll
        for (int j = 0; j < 8; ++j) acc[i][j] = 0.f;

    #pragma unroll 2
    for (int k = 0; k < 128; ++k) {
        uint4 au = *(const uint4*)&Asu[k][ty * 8];
        uint4 bu = *(const uint4*)&Bsu[k][tx * 8];
        float a[8] = {bflo(au.x), bfhi(au.x), bflo(au.y), bfhi(au.y),
                      bflo(au.z), bfhi(au.z), bflo(au.w), bfhi(au.w)};
        float b[8] = {bflo(bu.x), bfhi(bu.x), bflo(bu.y), bfhi(bu.y),
                      bflo(bu.z), bfhi(bu.z), bflo(bu.w), bfhi(bu.w)};
        #pragma unroll
        for (int i = 0; i < 8; ++i)
            #pragma unroll
            for (int j = 0; j < 8; ++j)
                acc[i][j] = fmaf(a[i], b[j], acc[i][j]);
    }

    float c2v[8];
    #pragma unroll
    for (int j = 0; j < 8; ++j) c2v[j] = c2[tx * 8 + j];
    #pragma unroll
    for (int i = 0; i < 8; ++i) {
        int row = rowBase + ty * 8 + i;
        if (row < n_nodes) {
            uint4 o;
            o.x = bf16rne(acc[i][0] + c2v[0]) | (bf16rne(acc[i][1] + c2v[1]) << 16);
            o.y = bf16rne(acc[i][2] + c2v[2]) | (bf16rne(acc[i][3] + c2v[3]) << 16);
            o.z = bf16rne(acc[i][4] + c2v[4]) | (bf16rne(acc[i][5] + c2v[5]) << 16);
            o.w = bf16rne(acc[i][6] + c2v[6]) | (bf16rne(acc[i][7] + c2v[7]) << 16);
            *(uint4*)&Vmb[row * 64 + tx * 4] = o;
        }
    }
}

// one thread per edge: e_val, gamma, b + deg histogram
__global__ void __launch_bounds__(256) edge1_kernel(
    const int* __restrict__ ei, const int* __restrict__ et,
    const float4* __restrict__ erf,
    const float4* __restrict__ w1t, const float2* __restrict__ w12,
    const float* __restrict__ rule_b2, const float* __restrict__ grw,
    const float2* __restrict__ srcPack, const float2* __restrict__ dstPack,
    const float* __restrict__ relA, const float* __restrict__ consts,
    float* __restrict__ e_val, float* __restrict__ gamma_out,
    float* __restrict__ b_out, int* __restrict__ deg,
    int n_edges)
{
    __shared__ float4 s_w1t[128];
    __shared__ float2 s_w12[128];
    int tid = threadIdx.x;
    if (tid < 128) { s_w1t[tid] = w1t[tid]; s_w12[tid] = w12[tid]; }
    __syncthreads();
    int e = blockIdx.x * 256 + tid;
    if (e >= n_edges) return;

    int s = ei[e], d = ei[n_edges + e], t = et[e];
    float4 rf = erf[e];
    float2 ss = srcPack[s], dd = dstPack[d];

    float pre = ss.x + dd.x + relA[t] + consts[0];
    float e_base = pre >= 0.f ? pre : 0.2f * pre;

    float b = rule_b2[0];
    #pragma unroll 8
    for (int j = 0; j < 128; ++j) {
        float4 w = s_w1t[j];
        float2 bw = s_w12[j];
        float h = fmaf(rf.x, w.x, fmaf(rf.y, w.y, fmaf(rf.z, w.z, fmaf(rf.w, w.w, bw.x))));
        b = fmaf(fmaxf(h, 0.f), bw.y, b);
    }

    float gl = fmaf(rf.x, grw[0], fmaf(rf.y, grw[1],
               fmaf(rf.z, grw[2], fmaf(rf.w, grw[3], consts[1] + ss.y + dd.y))));
    float gamma = 1.f / (1.f + __expf(-gl));

    gamma_out[e] = gamma;
    b_out[e] = b;
    e_val[e] = e_base + gamma * b;
    atomicAdd(&deg[d], 1);
}

// ---- CSR build: hierarchical scan of deg -> rowPtr ----
__global__ void __launch_bounds__(256) scan1_kernel(
    const int* __restrict__ deg, int* __restrict__ rowPtr,
    int* __restrict__ partials, int n)
{
    __shared__ int sdata[256];
    int tid = threadIdx.x;
    int base = blockIdx.x * 1024 + tid * 4;
    int v0 = (base + 0 < n) ? deg[base + 0] : 0;
    int v1 = (base + 1 < n) ? deg[base + 1] : 0;
    int v2 = (base + 2 < n) ? deg[base + 2] : 0;
    int v3 = (base + 3 < n) ? deg[base + 3] : 0;
    int tsum = v0 + v1 + v2 + v3;
    sdata[tid] = tsum;
    __syncthreads();
    #pragma unroll
    for (int off = 1; off < 256; off <<= 1) {
        int t = (tid >= off) ? sdata[tid - off] : 0;
        __syncthreads();
        sdata[tid] += t;
        __syncthreads();
    }
    int excl = sdata[tid] - tsum;
    if (base + 0 < n) rowPtr[base + 0] = excl;
    if (base + 1 < n) rowPtr[base + 1] = excl + v0;
    if (base + 2 < n) rowPtr[base + 2] = excl + v0 + v1;
    if (base + 3 < n) rowPtr[base + 3] = excl + v0 + v1 + v2;
    if (tid == 255) partials[blockIdx.x] = sdata[255];
}

__global__ void __launch_bounds__(64) scan2_kernel(int* __restrict__ partials, int nb)
{
    int lane = threadIdx.x;
    int v = (lane < nb) ? partials[lane] : 0;
    int orig = v;
    #pragma unroll
    for (int off = 1; off < 64; off <<= 1) {
        int t = __shfl_up(v, off, 64);
        if (lane >= off) v += t;
    }
    if (lane < nb) partials[lane] = v - orig;
}

// finalize rowPtr + init per-bucket cursors (bucket = dst >> 8)
__global__ void __launch_bounds__(256) scan3_kernel(
    int* __restrict__ rowPtr, const int* __restrict__ partials,
    int* __restrict__ bucketCursor, int n, int n_edges)
{
    int off = partials[blockIdx.x];
    int base = blockIdx.x * 1024 + threadIdx.x * 4;
    #pragma unroll
    for (int k = 0; k < 4; ++k) {
        int idx = base + k;
        if (idx < n) {
            int r = rowPtr[idx] + off;
            rowPtr[idx] = r;
            if ((idx & 255) == 0) bucketCursor[idx >> 8] = r;
        }
    }
    if (blockIdx.x == 0 && threadIdx.x == 0) rowPtr[n] = n_edges;
}

// sort1: LDS-binned coarse scatter into bucket regions (bucket = dst >> 8).
// 4096 edges/block; writes are bucket-ordered runs -> mostly coalesced.
// tmp payload: {e_val, src(16b) | type(4b)<<16 | (dst&255)<<20}
__global__ void __launch_bounds__(256) sort1_kernel(
    const int* __restrict__ ei, const int* __restrict__ et,
    const float* __restrict__ e_val, int* __restrict__ bucketCursor,
    float2* __restrict__ tmp, int n_edges)
{
    __shared__ float2 data[4096];          // 32 KB
    __shared__ unsigned char slotB[4096];  // 4 KB
    __shared__ int cnt[256], rk[256], base_[256], run[256], scanBuf[256];
    const int tid = threadIdx.x;
    const int blockBase = blockIdx.x * 4096;
    const int total = min(4096, n_edges - blockBase);

    cnt[tid] = 0;
    rk[tid] = 0;
    __syncthreads();

    int   d_[16];
    float ev_[16];
    int   pk_[16];
    #pragma unroll
    for (int i = 0; i < 16; ++i) {
        int e = blockBase + i * 256 + tid;
        if (e < n_edges) {
            int d = ei[n_edges + e];
            d_[i]  = d;
            ev_[i] = e_val[e];
            pk_[i] = (ei[e] & 0xFFFF) | ((et[e] & 15) << 16) | ((d & 255) << 20);
            atomicAdd(&cnt[d >> 8], 1);
        } else {
            d_[i] = -1;
        }
    }
    __syncthreads();

    // exclusive scan of cnt (256)
    int c = cnt[tid];
    scanBuf[tid] = c;
    __syncthreads();
    #pragma unroll
    for (int off = 1; off < 256; off <<= 1) {
        int t = (tid >= off) ? scanBuf[tid - off] : 0;
        __syncthreads();
        scanBuf[tid] += t;
        __syncthreads();
    }
    base_[tid] = scanBuf[tid] - c;
    // reserve global run in this bucket's final region
    run[tid] = c ? atomicAdd(&bucketCursor[tid], c) : 0;
    __syncthreads();

    // bin edges into LDS in bucket order
    #pragma unroll
    for (int i = 0; i < 16; ++i) {
        if (d_[i] >= 0) {
            int b = d_[i] >> 8;
            int r = atomicAdd(&rk[b], 1);
            int slot = base_[b] + r;
            data[slot] = make_float2(ev_[i], __int_as_float(pk_[i]));
            slotB[slot] = (unsigned char)b;
        }
    }
    __syncthreads();

    // stream LDS -> global: consecutive slots -> consecutive addresses per run
    for (int j = tid; j < total; j += 256) {
        int b = slotB[j];
        tmp[run[b] + (j - base_[b])] = data[j];
    }
}

// sort2: per-bucket exact CSR placement via LDS cursors (256 dsts/bucket).
// Writes stay inside a ~32KB window -> L2-resident, HBM write ~= 1x.
__global__ void __launch_bounds__(256) sort2_kernel(
    const int* __restrict__ rowPtr, const float2* __restrict__ tmp,
    float2* __restrict__ payload, int n_nodes)
{
    __shared__ int cur[256];
    const int tid = threadIdx.x;
    const int d0 = blockIdx.x * 256;
    const int dEnd = min(d0 + 256, n_nodes);
    if (d0 + tid < dEnd) cur[tid] = rowPtr[d0 + tid];
    __syncthreads();
    const int lo = rowPtr[d0];
    const int hi = rowPtr[dEnd];
    for (int j = lo + tid; j < hi; j += 256) {
        float2 p = tmp[j];
        unsigned pk = __float_as_uint(p.y);
        int dl = (pk >> 20) & 255;
        int pos = atomicAdd(&cur[dl], 1);
        unsigned st = (pk & 0xFFFFu) | (((pk >> 16) & 15u) << 27);
        payload[pos] = make_float2(p.x, __uint_as_float(st));
    }
}

// one wave per dst node: coalesced payload, shuffle softmax, batch-4 gather.
__global__ void __launch_bounds__(256) gather_kernel(
    const int* __restrict__ rowPtr, const float2* __restrict__ payload,
    const unsigned* __restrict__ Vmb, const float* __restrict__ relM,
    float* __restrict__ out, float2* __restrict__ nodeMS, int n_nodes)
{
    int lane = threadIdx.x & 63;
    int d = blockIdx.x * 4 + (threadIdx.x >> 6);
    if (d >= n_nodes) return;
    int start = rowPtr[d];
    int deg = rowPtr[d + 1] - start;

    float acc0 = 0.f, acc1 = 0.f;
    float m = -INFINITY, inv;

    // batch-4 accumulation: 4 independent Vmb/relM loads in flight
    auto acc4 = [&](float av, int st, int k) {
        float a[4];
        int s[4];
        #pragma unroll
        for (int i = 0; i < 4; ++i) {
            a[i] = __shfl(av, k + i, 64);   // padded lanes carry av=0
            s[i] = __shfl(st, k + i, 64);
        }
        unsigned v[4];
        float2 rm[4];
        #pragma unroll
        for (int i = 0; i < 4; ++i) {
            int ss = s[i] & 0x7FFFFFF;
            int tt = ((unsigned)s[i]) >> 27;
            v[i]  = Vmb[ss * 64 + lane];
            rm[i] = *(const float2*)&relM[tt * 128 + lane * 2];
        }
        #pragma unroll
        for (int i = 0; i < 4; ++i) {
            acc0 = fmaf(a[i], bflo(v[i]) + rm[i].x, acc0);
            acc1 = fmaf(a[i], bfhi(v[i]) + rm[i].y, acc1);
        }
    };

    if (deg <= 64) {
        float ev = -INFINITY;
        int st = 0;
        if (lane < deg) {
            float2 p = payload[start + lane];
            ev = p.x;
            st = __float_as_int(p.y);
        }
        m = wave_max(ev);
        float ex = (lane < deg) ? __expf(ev - m) : 0.f;
        float sum = wave_sum(ex);
        inv = 1.f / (sum + 1e-16f);
        float av = ex * inv;                 // 0 in padded lanes
        for (int k = 0; k < deg; k += 4) acc4(av, st, k);
    } else {
        for (int i = lane; i < deg; i += 64) m = fmaxf(m, payload[start + i].x);
        m = wave_max(m);
        float sum = 0.f;
        for (int i = lane; i < deg; i += 64) sum += __expf(payload[start + i].x - m);
        sum = wave_sum(sum);
        inv = 1.f / (sum + 1e-16f);
        for (int c = 0; c < deg; c += 64) {
            int i = c + lane;
            float av = 0.f;
            int st = 0;
            if (i < deg) {
                float2 p = payload[start + i];
                av = __expf(p.x - m) * inv;
                st = __float_as_int(p.y);
            }
            int cnt = min(64, deg - c);
            for (int k = 0; k < cnt; k += 4) acc4(av, st, k);
        }
    }
    if (lane == 0) nodeMS[d] = make_float2(m, inv);
    *(float2*)&out[d * 128 + lane * 2] = make_float2(acc0, acc1);
}

// fully-coalesced alpha: alpha[e] = exp(e_val[e] - m[d]) * inv[d]
__global__ void __launch_bounds__(256) alpha_kernel(
    const int* __restrict__ ei, const float* __restrict__ e_val,
    const float2* __restrict__ nodeMS, float* __restrict__ alpha_out, int n_edges)
{
    int e = blockIdx.x * blockDim.x + threadIdx.x;
    if (e >= n_edges) return;
    int d = ei[n_edges + e];
    float2 ms = nodeMS[d];
    alpha_out[e] = __expf(e_val[e] - ms.x) * ms.y;
}

extern "C" void kernel_launch(void* const* d_in, const int* in_sizes, int n_in,
                              void* d_out, int out_size, void* d_ws, size_t ws_size,
                              hipStream_t stream)
{
    const float* x        = (const float*)d_in[0];
    const int*   ei       = (const int*)d_in[1];
    const int*   et       = (const int*)d_in[2];
    const float* erf      = (const float*)d_in[3];
    const float* Wq       = (const float*)d_in[5];
    const float* bq       = (const float*)d_in[6];
    const float* Wk       = (const float*)d_in[7];
    const float* bk       = (const float*)d_in[8];
    const float* Wv       = (const float*)d_in[9];
    const float* bv       = (const float*)d_in[10];
    const float* rel_emb  = (const float*)d_in[11];
    const float* attn_vec = (const float*)d_in[12];
    const float* rule_w1  = (const float*)d_in[13];
    const float* rule_b1  = (const float*)d_in[14];
    const float* rule_w2  = (const float*)d_in[15];
    const float* rule_b2  = (const float*)d_in[16];
    const float* grw      = (const float*)d_in[17];
    const float* grb      = (const float*)d_in[18];
    const float* gnw      = (const float*)d_in[19];
    const float* gnb      = (const float*)d_in[20];
    const float* msg_w    = (const float*)d_in[21];
    const float* msg_b    = (const float*)d_in[22];

    const int n_nodes = in_sizes[0] / 128;
    const int n_edges = in_sizes[2];
    const int nb = (n_nodes + 1023) / 1024;   // scan blocks (<= 64 required)
    const int nbuck = (n_nodes + 255) / 256;  // coarse buckets

    float* ws = (float*)d_ws;
    size_t off = 0;
    unsigned* Vmb  = (unsigned*)(ws + off); off += (size_t)n_nodes * 64;
    float2* payload = (float2*)(ws + off); off += 2 * (size_t)n_edges;
    float2* tmpPay  = (float2*)(ws + off); off += 2 * (size_t)n_edges;
    float* e_val   = ws + off; off += n_edges;
    float* srcPack = ws + off; off += 2 * (size_t)n_nodes;
    float* dstPack = ws + off; off += 2 * (size_t)n_nodes;
    float2* nodeMS = (float2*)(ws + off); off += 2 * (size_t)n_nodes;
    int*   deg     = (int*)(ws + off); off += n_nodes;
    int*   rowPtr  = (int*)(ws + off); off += n_nodes + 4;
    int*   partials= (int*)(ws + off); off += 64;
    int*   bucketCursor = (int*)(ws + off); off += 256;
    unsigned short* W2b = (unsigned short*)(ws + off); off += 128 * 64;
    float* c2      = ws + off; off += 128;
    float* wkA     = ws + off; off += 128;
    float* wqA     = ws + off; off += 128;
    float* wkG     = ws + off; off += 128;
    float* wqG     = ws + off; off += 128;
    float* relA    = ws + off; off += 16;
    float* relM    = ws + off; off += 16 * 128;
    float* consts  = ws + off; off += 2;
    off += 2;  // 16B alignment for w1t
    float4* w1t    = (float4*)(ws + off); off += 128 * 4;
    float2* w12    = (float2*)(ws + off); off += 128 * 2;

    float* out       = (float*)d_out;
    float* alpha_out = out + (size_t)n_nodes * 128;
    float* gamma_out = alpha_out + n_edges;
    float* b_out     = gamma_out + n_edges;

    hipLaunchKernelGGL(precompute_kernel, dim3(146), dim3(128), 0, stream,
                       Wq, bq, Wk, bk, Wv, bv, rel_emb, attn_vec, msg_w, msg_b,
                       gnw, grb, gnb, rule_w1, rule_b1, rule_w2,
                       W2b, c2, wkA, wqA, wkG, wqG, relA, relM, consts, w1t, w12);

    hipLaunchKernelGGL(node_kernel, dim3((n_nodes + 127) / 128), dim3(256), 0, stream,
                       (const float4*)x, W2b, c2,
                       wkA, wqA, wkG, wqG, Vmb, (float2*)srcPack, (float2*)dstPack,
                       deg, n_nodes);

    hipLaunchKernelGGL(edge1_kernel, dim3((n_edges + 255) / 256), dim3(256), 0, stream,
                       ei, et, (const float4*)erf, (const float4*)w1t, (const float2*)w12,
                       rule_b2, grw, (const float2*)srcPack, (const float2*)dstPack,
                       relA, consts, e_val, gamma_out, b_out, deg, n_edges);

    hipLaunchKernelGGL(scan1_kernel, dim3(nb), dim3(256), 0, stream,
                       deg, rowPtr, partials, n_nodes);
    hipLaunchKernelGGL(scan2_kernel, dim3(1), dim3(64), 0, stream,
                       partials, nb);
    hipLaunchKernelGGL(scan3_kernel, dim3(nb), dim3(256), 0, stream,
                       rowPtr, partials, bucketCursor, n_nodes, n_edges);

    hipLaunchKernelGGL(sort1_kernel, dim3((n_edges + 4095) / 4096), dim3(256), 0, stream,
                       ei, et, e_val, bucketCursor, tmpPay, n_edges);

    hipLaunchKernelGGL(sort2_kernel, dim3(nbuck), dim3(256), 0, stream,
                       rowPtr, tmpPay, payload, n_nodes);

    hipLaunchKernelGGL(gather_kernel, dim3((n_nodes + 3) / 4), dim3(256), 0, stream,
                       rowPtr, payload, Vmb, relM, out, nodeMS, n_nodes);

    hipLaunchKernelGGL(alpha_kernel, dim3((n_edges + 255) / 256), dim3(256), 0, stream,
                       ei, e_val, nodeMS, alpha_out, n_edges);
}

// Round 8
// 279.856 us; speedup vs baseline: 1.5130x; 1.0578x over previous
//
#include <hip/hip_runtime.h>
#include <math.h>

// ---------------------------------------------------------------------------
// RGAPConv, CSR-gather formulation (R8 = R7 with MFMA node GEMM):
//   node:      MFMA bf16 GEMM (16x16x32), 128x128 tile, wave-per-64x64
//              quadrant; A row-major LDS, B transposed LDS (both b128 frag
//              reads); epilogue packs bf16 pairs via shfl_xor. Vm bf16.
//   edge1:     e_val/gamma/b + dst histogram.
//   CSR build: scan1/2/3 -> sort1 (coarse LDS-binned) -> sort2 (exact, L2).
//   gather:    one wave per dst node, shuffle softmax, batch-4 accumulation.
//   alpha:     coalesced per-edge kernel from per-node {m, inv}.
// ---------------------------------------------------------------------------

using bf16x8 = __attribute__((ext_vector_type(8))) short;
using f32x4  = __attribute__((ext_vector_type(4))) float;

__device__ __forceinline__ float wave_max(float v) {
    #pragma unroll
    for (int o = 32; o > 0; o >>= 1) v = fmaxf(v, __shfl_xor(v, o, 64));
    return v;
}
__device__ __forceinline__ float wave_sum(float v) {
    #pragma unroll
    for (int o = 32; o > 0; o >>= 1) v += __shfl_xor(v, o, 64);
    return v;
}

__device__ __forceinline__ unsigned bf16rne(float f) {
    unsigned u = __float_as_uint(f);
    return (u + 0x7FFFu + ((u >> 16) & 1u)) >> 16;  // round-to-nearest-even
}
__device__ __forceinline__ float bflo(unsigned u) { return __uint_as_float(u << 16); }
__device__ __forceinline__ float bfhi(unsigned u) { return __uint_as_float(u & 0xFFFF0000u); }

// grid = 146 blocks x 128 threads. Builds all small tables.
// W2bT is stored TRANSPOSED: W2bT[n*128 + k] = (Wv@msg_w)[k][n] in bf16.
__global__ void __launch_bounds__(128) precompute_kernel(
    const float* __restrict__ Wq, const float* __restrict__ bq,
    const float* __restrict__ Wk, const float* __restrict__ bk,
    const float* __restrict__ Wv, const float* __restrict__ bv,
    const float* __restrict__ rel_emb, const float* __restrict__ attn_vec,
    const float* __restrict__ msg_w, const float* __restrict__ msg_b,
    const float* __restrict__ gnw, const float* __restrict__ grb,
    const float* __restrict__ gnb,
    const float* __restrict__ rule_w1, const float* __restrict__ rule_b1,
    const float* __restrict__ rule_w2,
    unsigned short* __restrict__ W2bT, float* __restrict__ c2,
    float* __restrict__ wkA, float* __restrict__ wqA,
    float* __restrict__ wkG, float* __restrict__ wqG,
    float* __restrict__ relA, float* __restrict__ relM,
    float* __restrict__ consts,
    float4* __restrict__ w1t, float2* __restrict__ w12)
{
    __shared__ float red[128];
    int bid = blockIdx.x, j = threadIdx.x;

    auto blk_reduce = [&](float v) -> float {
        red[j] = v;
        __syncthreads();
        for (int s = 64; s > 0; s >>= 1) {
            if (j < s) red[j] += red[j + s];
            __syncthreads();
        }
        float r = red[0];
        __syncthreads();
        return r;
    };

    if (bid < 128) {
        int i = bid;  // k index
        float acc = 0.f;
        #pragma unroll 8
        for (int k = 0; k < 128; ++k) acc = fmaf(Wv[i * 128 + k], msg_w[k * 128 + j], acc);
        W2bT[j * 128 + i] = (unsigned short)bf16rne(acc);  // transposed store
        float r;
        r = blk_reduce(Wk[i * 128 + j] * attn_vec[j]);        if (j == 0) wkA[i] = r;
        r = blk_reduce(Wq[i * 128 + j] * attn_vec[128 + j]);  if (j == 0) wqA[i] = r;
        r = blk_reduce(Wk[i * 128 + j] * gnw[j]);             if (j == 0) wkG[i] = r;
        r = blk_reduce(Wq[i * 128 + j] * gnw[128 + j]);       if (j == 0) wqG[i] = r;
    } else if (bid < 144) {
        int t = bid - 128;
        float acc = 0.f;
        #pragma unroll 8
        for (int k = 0; k < 128; ++k) acc = fmaf(rel_emb[t * 128 + k], msg_w[k * 128 + j], acc);
        relM[t * 128 + j] = acc;
        float r = blk_reduce(rel_emb[t * 128 + j] * attn_vec[256 + j]);
        if (j == 0) relA[t] = r;
    } else if (bid == 144) {
        float acc = msg_b[j];
        #pragma unroll 8
        for (int k = 0; k < 128; ++k) acc = fmaf(bv[k], msg_w[k * 128 + j], acc);
        c2[j] = acc;
        w1t[j] = make_float4(rule_w1[j], rule_w1[128 + j], rule_w1[256 + j], rule_w1[384 + j]);
        w12[j] = make_float2(rule_b1[j], rule_w2[j]);
    } else {
        float r = blk_reduce(bk[j] * attn_vec[j] + bq[j] * attn_vec[128 + j]);
        if (j == 0) consts[0] = r;
        r = blk_reduce(bk[j] * gnw[j] + bq[j] * gnw[128 + j]);
        if (j == 0) consts[1] = r + grb[0] + gnb[0];
    }
}

// MFMA node GEMM: 128x128 tile/block, 4 waves each own a 64x64 quadrant.
// As[m][k] row-major bf16 (A-frag: 8 contiguous k per lane);
// Bs[n][k] = W2^T bf16 (B-frag: 8 contiguous k per lane). Rows padded to 136.
__global__ void __launch_bounds__(256) node_kernel(
    const float4* __restrict__ x4, const unsigned short* __restrict__ W2bT,
    const float* __restrict__ c2,
    const float* __restrict__ wkA, const float* __restrict__ wqA,
    const float* __restrict__ wkG, const float* __restrict__ wqG,
    unsigned* __restrict__ Vmb, float2* __restrict__ srcPack,
    float2* __restrict__ dstPack, int* __restrict__ deg, int n_nodes)
{
    __shared__ unsigned short Asu[128][136];
    __shared__ unsigned short Bsu[128][136];
    const int tid = threadIdx.x;
    const int rowBase = blockIdx.x * 128;

    if (tid < 128 && rowBase + tid < n_nodes) deg[rowBase + tid] = 0;

    // stage x -> As[m][k] bf16: lanes cover 32 k4-groups of one row each iter
    #pragma unroll
    for (int l = 0; l < 16; ++l) {
        int flat = l * 256 + tid;       // 4096 = 128 rows x 32 k4
        int r = flat >> 5, k4 = flat & 31;
        int row = rowBase + r;
        float4 v = (row < n_nodes) ? x4[row * 32 + k4] : make_float4(0.f, 0.f, 0.f, 0.f);
        uint2 u;
        u.x = bf16rne(v.x) | (bf16rne(v.y) << 16);
        u.y = bf16rne(v.z) | (bf16rne(v.w) << 16);
        *(uint2*)&Asu[r][k4 * 4] = u;
    }
    // stage W2^T -> Bs[n][k] bf16 (already bf16 in global, coalesced 8B)
    #pragma unroll
    for (int l = 0; l < 16; ++l) {
        int flat = l * 256 + tid;       // 4096 = 128 n x 32 kq
        int n = flat >> 5, kq = flat & 31;
        uint2 w = *(const uint2*)&W2bT[n * 128 + kq * 4];
        *(uint2*)&Bsu[n][kq * 4] = w;
    }

    // fp32 per-node scalar packs from global x (L2-hot after staging)
    {
        int r = tid & 127, h = tid >> 7;
        int row = rowBase + r;
        if (row < n_nodes) {
            const float4* wa4 = (const float4*)(h ? wqA : wkA);
            const float4* wg4 = (const float4*)(h ? wqG : wkG);
            float sA = 0.f, sG = 0.f;
            #pragma unroll 8
            for (int k4 = 0; k4 < 32; ++k4) {
                float4 xv = x4[row * 32 + k4];
                float4 wa = wa4[k4], wg = wg4[k4];
                sA = fmaf(xv.x, wa.x, fmaf(xv.y, wa.y, fmaf(xv.z, wa.z, fmaf(xv.w, wa.w, sA))));
                sG = fmaf(xv.x, wg.x, fmaf(xv.y, wg.y, fmaf(xv.z, wg.z, fmaf(xv.w, wg.w, sG))));
            }
            if (h) dstPack[row] = make_float2(sA, sG);
            else   srcPack[row] = make_float2(sA, sG);
        }
    }
    __syncthreads();

    const int wave = tid >> 6, lane = tid & 63;
    const int ln = lane & 15, quad = lane >> 4;
    const int wm = (wave & 1) * 64, wn = (wave >> 1) * 64;

    f32x4 acc[4][4];
    #pragma unroll
    for (int i = 0; i < 4; ++i)
        #pragma unroll
        for (int j = 0; j < 4; ++j) acc[i][j] = (f32x4){0.f, 0.f, 0.f, 0.f};

    #pragma unroll
    for (int kc = 0; kc < 4; ++kc) {
        int k0 = kc * 32 + quad * 8;
        bf16x8 afr[4], bfr[4];
        #pragma unroll
        for (int mt = 0; mt < 4; ++mt)
            afr[mt] = *(const bf16x8*)&Asu[wm + mt * 16 + ln][k0];
        #pragma unroll
        for (int nt = 0; nt < 4; ++nt)
            bfr[nt] = *(const bf16x8*)&Bsu[wn + nt * 16 + ln][k0];
        #pragma unroll
        for (int mt = 0; mt < 4; ++mt)
            #pragma unroll
            for (int nt = 0; nt < 4; ++nt)
                acc[mt][nt] = __builtin_amdgcn_mfma_f32_16x16x32_bf16(
                    afr[mt], bfr[nt], acc[mt][nt], 0, 0, 0);
    }

    // epilogue: D col = ln, row = quad*4 + reg; pack col pairs via shfl_xor(1)
    #pragma unroll
    for (int nt = 0; nt < 4; ++nt) {
        int col = wn + nt * 16 + ln;
        float cb = c2[col];
        #pragma unroll
        for (int mt = 0; mt < 4; ++mt) {
            #pragma unroll
            for (int r = 0; r < 4; ++r) {
                int row = rowBase + wm + mt * 16 + quad * 4 + r;
                float v = acc[mt][nt][r] + cb;
                float pv = __shfl_xor(v, 1, 64);
                if (!(ln & 1) && row < n_nodes) {
                    Vmb[row * 64 + (col >> 1)] = bf16rne(v) | (bf16rne(pv) << 16);
                }
            }
        }
    }
}

// one thread per edge: e_val, gamma, b + deg histogram
__global__ void __launch_bounds__(256) edge1_kernel(
    const int* __restrict__ ei, const int* __restrict__ et,
    const float4* __restrict__ erf,
    const float4* __restrict__ w1t, const float2* __restrict__ w12,
    const float* __restrict__ rule_b2, const float* __restrict__ grw,
    const float2* __restrict__ srcPack, const float2* __restrict__ dstPack,
    const float* __restrict__ relA, const float* __restrict__ consts,
    float* __restrict__ e_val, float* __restrict__ gamma_out,
    float* __restrict__ b_out, int* __restrict__ deg,
    int n_edges)
{
    __shared__ float4 s_w1t[128];
    __shared__ float2 s_w12[128];
    int tid = threadIdx.x;
    if (tid < 128) { s_w1t[tid] = w1t[tid]; s_w12[tid] = w12[tid]; }
    __syncthreads();
    int e = blockIdx.x * 256 + tid;
    if (e >= n_edges) return;

    int s = ei[e], d = ei[n_edges + e], t = et[e];
    float4 rf = erf[e];
    float2 ss = srcPack[s], dd = dstPack[d];

    float pre = ss.x + dd.x + relA[t] + consts[0];
    float e_base = pre >= 0.f ? pre : 0.2f * pre;

    float b = rule_b2[0];
    #pragma unroll 8
    for (int j = 0; j < 128; ++j) {
        float4 w = s_w1t[j];
        float2 bw = s_w12[j];
        float h = fmaf(rf.x, w.x, fmaf(rf.y, w.y, fmaf(rf.z, w.z, fmaf(rf.w, w.w, bw.x))));
        b = fmaf(fmaxf(h, 0.f), bw.y, b);
    }

    float gl = fmaf(rf.x, grw[0], fmaf(rf.y, grw[1],
               fmaf(rf.z, grw[2], fmaf(rf.w, grw[3], consts[1] + ss.y + dd.y))));
    float gamma = 1.f / (1.f + __expf(-gl));

    gamma_out[e] = gamma;
    b_out[e] = b;
    e_val[e] = e_base + gamma * b;
    atomicAdd(&deg[d], 1);
}

// ---- CSR build: hierarchical scan of deg -> rowPtr ----
__global__ void __launch_bounds__(256) scan1_kernel(
    const int* __restrict__ deg, int* __restrict__ rowPtr,
    int* __restrict__ partials, int n)
{
    __shared__ int sdata[256];
    int tid = threadIdx.x;
    int base = blockIdx.x * 1024 + tid * 4;
    int v0 = (base + 0 < n) ? deg[base + 0] : 0;
    int v1 = (base + 1 < n) ? deg[base + 1] : 0;
    int v2 = (base + 2 < n) ? deg[base + 2] : 0;
    int v3 = (base + 3 < n) ? deg[base + 3] : 0;
    int tsum = v0 + v1 + v2 + v3;
    sdata[tid] = tsum;
    __syncthreads();
    #pragma unroll
    for (int off = 1; off < 256; off <<= 1) {
        int t = (tid >= off) ? sdata[tid - off] : 0;
        __syncthreads();
        sdata[tid] += t;
        __syncthreads();
    }
    int excl = sdata[tid] - tsum;
    if (base + 0 < n) rowPtr[base + 0] = excl;
    if (base + 1 < n) rowPtr[base + 1] = excl + v0;
    if (base + 2 < n) rowPtr[base + 2] = excl + v0 + v1;
    if (base + 3 < n) rowPtr[base + 3] = excl + v0 + v1 + v2;
    if (tid == 255) partials[blockIdx.x] = sdata[255];
}

__global__ void __launch_bounds__(64) scan2_kernel(int* __restrict__ partials, int nb)
{
    int lane = threadIdx.x;
    int v = (lane < nb) ? partials[lane] : 0;
    int orig = v;
    #pragma unroll
    for (int off = 1; off < 64; off <<= 1) {
        int t = __shfl_up(v, off, 64);
        if (lane >= off) v += t;
    }
    if (lane < nb) partials[lane] = v - orig;
}

// finalize rowPtr + init per-bucket cursors (bucket = dst >> 8)
__global__ void __launch_bounds__(256) scan3_kernel(
    int* __restrict__ rowPtr, const int* __restrict__ partials,
    int* __restrict__ bucketCursor, int n, int n_edges)
{
    int off = partials[blockIdx.x];
    int base = blockIdx.x * 1024 + threadIdx.x * 4;
    #pragma unroll
    for (int k = 0; k < 4; ++k) {
        int idx = base + k;
        if (idx < n) {
            int r = rowPtr[idx] + off;
            rowPtr[idx] = r;
            if ((idx & 255) == 0) bucketCursor[idx >> 8] = r;
        }
    }
    if (blockIdx.x == 0 && threadIdx.x == 0) rowPtr[n] = n_edges;
}

// sort1: LDS-binned coarse scatter into bucket regions (bucket = dst >> 8).
__global__ void __launch_bounds__(256) sort1_kernel(
    const int* __restrict__ ei, const int* __restrict__ et,
    const float* __restrict__ e_val, int* __restrict__ bucketCursor,
    float2* __restrict__ tmp, int n_edges)
{
    __shared__ float2 data[4096];          // 32 KB
    __shared__ unsigned char slotB[4096];  // 4 KB
    __shared__ int cnt[256], rk[256], base_[256], run[256], scanBuf[256];
    const int tid = threadIdx.x;
    const int blockBase = blockIdx.x * 4096;
    const int total = min(4096, n_edges - blockBase);

    cnt[tid] = 0;
    rk[tid] = 0;
    __syncthreads();

    int   d_[16];
    float ev_[16];
    int   pk_[16];
    #pragma unroll
    for (int i = 0; i < 16; ++i) {
        int e = blockBase + i * 256 + tid;
        if (e < n_edges) {
            int d = ei[n_edges + e];
            d_[i]  = d;
            ev_[i] = e_val[e];
            pk_[i] = (ei[e] & 0xFFFF) | ((et[e] & 15) << 16) | ((d & 255) << 20);
            atomicAdd(&cnt[d >> 8], 1);
        } else {
            d_[i] = -1;
        }
    }
    __syncthreads();

    int c = cnt[tid];
    scanBuf[tid] = c;
    __syncthreads();
    #pragma unroll
    for (int off = 1; off < 256; off <<= 1) {
        int t = (tid >= off) ? scanBuf[tid - off] : 0;
        __syncthreads();
        scanBuf[tid] += t;
        __syncthreads();
    }
    base_[tid] = scanBuf[tid] - c;
    run[tid] = c ? atomicAdd(&bucketCursor[tid], c) : 0;
    __syncthreads();

    #pragma unroll
    for (int i = 0; i < 16; ++i) {
        if (d_[i] >= 0) {
            int b = d_[i] >> 8;
            int r = atomicAdd(&rk[b], 1);
            int slot = base_[b] + r;
            data[slot] = make_float2(ev_[i], __int_as_float(pk_[i]));
            slotB[slot] = (unsigned char)b;
        }
    }
    __syncthreads();

    for (int j = tid; j < total; j += 256) {
        int b = slotB[j];
        tmp[run[b] + (j - base_[b])] = data[j];
    }
}

// sort2: per-bucket exact CSR placement via LDS cursors (256 dsts/bucket).
__global__ void __launch_bounds__(256) sort2_kernel(
    const int* __restrict__ rowPtr, const float2* __restrict__ tmp,
    float2* __restrict__ payload, int n_nodes)
{
    __shared__ int cur[256];
    const int tid = threadIdx.x;
    const int d0 = blockIdx.x * 256;
    const int dEnd = min(d0 + 256, n_nodes);
    if (d0 + tid < dEnd) cur[tid] = rowPtr[d0 + tid];
    __syncthreads();
    const int lo = rowPtr[d0];
    const int hi = rowPtr[dEnd];
    for (int j = lo + tid; j < hi; j += 256) {
        float2 p = tmp[j];
        unsigned pk = __float_as_uint(p.y);
        int dl = (pk >> 20) & 255;
        int pos = atomicAdd(&cur[dl], 1);
        unsigned st = (pk & 0xFFFFu) | (((pk >> 16) & 15u) << 27);
        payload[pos] = make_float2(p.x, __uint_as_float(st));
    }
}

// one wave per dst node: coalesced payload, shuffle softmax, batch-4 gather.
__global__ void __launch_bounds__(256) gather_kernel(
    const int* __restrict__ rowPtr, const float2* __restrict__ payload,
    const unsigned* __restrict__ Vmb, const float* __restrict__ relM,
    float* __restrict__ out, float2* __restrict__ nodeMS, int n_nodes)
{
    int lane = threadIdx.x & 63;
    int d = blockIdx.x * 4 + (threadIdx.x >> 6);
    if (d >= n_nodes) return;
    int start = rowPtr[d];
    int deg = rowPtr[d + 1] - start;

    float acc0 = 0.f, acc1 = 0.f;
    float m = -INFINITY, inv;

    auto acc4 = [&](float av, int st, int k) {
        float a[4];
        int s[4];
        #pragma unroll
        for (int i = 0; i < 4; ++i) {
            a[i] = __shfl(av, k + i, 64);
            s[i] = __shfl(st, k + i, 64);
        }
        unsigned v[4];
        float2 rm[4];
        #pragma unroll
        for (int i = 0; i < 4; ++i) {
            int ss = s[i] & 0x7FFFFFF;
            int tt = ((unsigned)s[i]) >> 27;
            v[i]  = Vmb[ss * 64 + lane];
            rm[i] = *(const float2*)&relM[tt * 128 + lane * 2];
        }
        #pragma unroll
        for (int i = 0; i < 4; ++i) {
            acc0 = fmaf(a[i], bflo(v[i]) + rm[i].x, acc0);
            acc1 = fmaf(a[i], bfhi(v[i]) + rm[i].y, acc1);
        }
    };

    if (deg <= 64) {
        float ev = -INFINITY;
        int st = 0;
        if (lane < deg) {
            float2 p = payload[start + lane];
            ev = p.x;
            st = __float_as_int(p.y);
        }
        m = wave_max(ev);
        float ex = (lane < deg) ? __expf(ev - m) : 0.f;
        float sum = wave_sum(ex);
        inv = 1.f / (sum + 1e-16f);
        float av = ex * inv;
        for (int k = 0; k < deg; k += 4) acc4(av, st, k);
    } else {
        for (int i = lane; i < deg; i += 64) m = fmaxf(m, payload[start + i].x);
        m = wave_max(m);
        float sum = 0.f;
        for (int i = lane; i < deg; i += 64) sum += __expf(payload[start + i].x - m);
        sum = wave_sum(sum);
        inv = 1.f / (sum + 1e-16f);
        for (int c = 0; c < deg; c += 64) {
            int i = c + lane;
            float av = 0.f;
            int st = 0;
            if (i < deg) {
                float2 p = payload[start + i];
                av = __expf(p.x - m) * inv;
                st = __float_as_int(p.y);
            }
            int cnt = min(64, deg - c);
            for (int k = 0; k < cnt; k += 4) acc4(av, st, k);
        }
    }
    if (lane == 0) nodeMS[d] = make_float2(m, inv);
    *(float2*)&out[d * 128 + lane * 2] = make_float2(acc0, acc1);
}

// fully-coalesced alpha: alpha[e] = exp(e_val[e] - m[d]) * inv[d]
__global__ void __launch_bounds__(256) alpha_kernel(
    const int* __restrict__ ei, const float* __restrict__ e_val,
    const float2* __restrict__ nodeMS, float* __restrict__ alpha_out, int n_edges)
{
    int e = blockIdx.x * blockDim.x + threadIdx.x;
    if (e >= n_edges) return;
    int d = ei[n_edges + e];
    float2 ms = nodeMS[d];
    alpha_out[e] = __expf(e_val[e] - ms.x) * ms.y;
}

extern "C" void kernel_launch(void* const* d_in, const int* in_sizes, int n_in,
                              void* d_out, int out_size, void* d_ws, size_t ws_size,
                              hipStream_t stream)
{
    const float* x        = (const float*)d_in[0];
    const int*   ei       = (const int*)d_in[1];
    const int*   et       = (const int*)d_in[2];
    const float* erf      = (const float*)d_in[3];
    const float* Wq       = (const float*)d_in[5];
    const float* bq       = (const float*)d_in[6];
    const float* Wk       = (const float*)d_in[7];
    const float* bk       = (const float*)d_in[8];
    const float* Wv       = (const float*)d_in[9];
    const float* bv       = (const float*)d_in[10];
    const float* rel_emb  = (const float*)d_in[11];
    const float* attn_vec = (const float*)d_in[12];
    const float* rule_w1  = (const float*)d_in[13];
    const float* rule_b1  = (const float*)d_in[14];
    const float* rule_w2  = (const float*)d_in[15];
    const float* rule_b2  = (const float*)d_in[16];
    const float* grw      = (const float*)d_in[17];
    const float* grb      = (const float*)d_in[18];
    const float* gnw      = (const float*)d_in[19];
    const float* gnb      = (const float*)d_in[20];
    const float* msg_w    = (const float*)d_in[21];
    const float* msg_b    = (const float*)d_in[22];

    const int n_nodes = in_sizes[0] / 128;
    const int n_edges = in_sizes[2];
    const int nb = (n_nodes + 1023) / 1024;   // scan blocks (<= 64 required)
    const int nbuck = (n_nodes + 255) / 256;  // coarse buckets

    float* ws = (float*)d_ws;
    size_t off = 0;
    unsigned* Vmb  = (unsigned*)(ws + off); off += (size_t)n_nodes * 64;
    float2* payload = (float2*)(ws + off); off += 2 * (size_t)n_edges;
    float2* tmpPay  = (float2*)(ws + off); off += 2 * (size_t)n_edges;
    float* e_val   = ws + off; off += n_edges;
    float* srcPack = ws + off; off += 2 * (size_t)n_nodes;
    float* dstPack = ws + off; off += 2 * (size_t)n_nodes;
    float2* nodeMS = (float2*)(ws + off); off += 2 * (size_t)n_nodes;
    int*   deg     = (int*)(ws + off); off += n_nodes;
    int*   rowPtr  = (int*)(ws + off); off += n_nodes + 4;
    int*   partials= (int*)(ws + off); off += 64;
    int*   bucketCursor = (int*)(ws + off); off += 256;
    unsigned short* W2bT = (unsigned short*)(ws + off); off += 128 * 64;
    float* c2      = ws + off; off += 128;
    float* wkA     = ws + off; off += 128;
    float* wqA     = ws + off; off += 128;
    float* wkG     = ws + off; off += 128;
    float* wqG     = ws + off; off += 128;
    float* relA    = ws + off; off += 16;
    float* relM    = ws + off; off += 16 * 128;
    float* consts  = ws + off; off += 2;
    off += 2;  // 16B alignment for w1t
    float4* w1t    = (float4*)(ws + off); off += 128 * 4;
    float2* w12    = (float2*)(ws + off); off += 128 * 2;

    float* out       = (float*)d_out;
    float* alpha_out = out + (size_t)n_nodes * 128;
    float* gamma_out = alpha_out + n_edges;
    float* b_out     = gamma_out + n_edges;

    hipLaunchKernelGGL(precompute_kernel, dim3(146), dim3(128), 0, stream,
                       Wq, bq, Wk, bk, Wv, bv, rel_emb, attn_vec, msg_w, msg_b,
                       gnw, grb, gnb, rule_w1, rule_b1, rule_w2,
                       W2bT, c2, wkA, wqA, wkG, wqG, relA, relM, consts, w1t, w12);

    hipLaunchKernelGGL(node_kernel, dim3((n_nodes + 127) / 128), dim3(256), 0, stream,
                       (const float4*)x, W2bT, c2,
                       wkA, wqA, wkG, wqG, Vmb, (float2*)srcPack, (float2*)dstPack,
                       deg, n_nodes);

    hipLaunchKernelGGL(edge1_kernel, dim3((n_edges + 255) / 256), dim3(256), 0, stream,
                       ei, et, (const float4*)erf, (const float4*)w1t, (const float2*)w12,
                       rule_b2, grw, (const float2*)srcPack, (const float2*)dstPack,
                       relA, consts, e_val, gamma_out, b_out, deg, n_edges);

    hipLaunchKernelGGL(scan1_kernel, dim3(nb), dim3(256), 0, stream,
                       deg, rowPtr, partials, n_nodes);
    hipLaunchKernelGGL(scan2_kernel, dim3(1), dim3(64), 0, stream,
                       partials, nb);
    hipLaunchKernelGGL(scan3_kernel, dim3(nb), dim3(256), 0, stream,
                       rowPtr, partials, bucketCursor, n_nodes, n_edges);

    hipLaunchKernelGGL(sort1_kernel, dim3((n_edges + 4095) / 4096), dim3(256), 0, stream,
                       ei, et, e_val, bucketCursor, tmpPay, n_edges);

    hipLaunchKernelGGL(sort2_kernel, dim3(nbuck), dim3(256), 0, stream,
                       rowPtr, tmpPay, payload, n_nodes);

    hipLaunchKernelGGL(gather_kernel, dim3((n_nodes + 3) / 4), dim3(256), 0, stream,
                       rowPtr, payload, Vmb, relM, out, nodeMS, n_nodes);

    hipLaunchKernelGGL(alpha_kernel, dim3((n_edges + 255) / 256), dim3(256), 0, stream,
                       ei, e_val, nodeMS, alpha_out, n_edges);
}